// Round 1
// baseline (533.369 us; speedup 1.0000x reference)
//
#include <hip/hip_runtime.h>
#include <stdint.h>

// ---------------------------------------------------------------------------
// FalconMamba2 SSM decoder layer, MI355X (gfx950)
// Round 0: correctness-first. bf16 MFMA for in_proj/out_proj, fp32 VALU SSD.
// ---------------------------------------------------------------------------

typedef __bf16 bf16x8 __attribute__((ext_vector_type(8)));
typedef float  f32x4  __attribute__((ext_vector_type(4)));

#define DEVFN __device__ __forceinline__

DEVFN unsigned short f2b(float f) {
  uint32_t u = __builtin_bit_cast(uint32_t, f);
  u += 0x7fffu + ((u >> 16) & 1u);          // round-to-nearest-even
  return (unsigned short)(u >> 16);
}

// ---------------------------------------------------------------------------
// fp32 -> bf16 conversion with zero-padding tail (pad rows for GEMM tiles)
// ---------------------------------------------------------------------------
__global__ void f32_to_bf16_pad(const float* __restrict__ src,
                                unsigned short* __restrict__ dst,
                                long srcElems, long dstElems) {
  const long i = ((long)blockIdx.x * 256 + threadIdx.x) * 4;
  if (i >= dstElems) return;
  ushort4 o;
  if (i < srcElems) {
    float4 v = *reinterpret_cast<const float4*>(src + i);
    o.x = f2b(v.x); o.y = f2b(v.y); o.z = f2b(v.z); o.w = f2b(v.w);
  } else {
    o.x = 0; o.y = 0; o.z = 0; o.w = 0;
  }
  *reinterpret_cast<ushort4*>(dst + i) = o;
}

// ---------------------------------------------------------------------------
// input RMSNorm: x[2048][2048] f32 -> h bf16
// ---------------------------------------------------------------------------
__global__ __launch_bounds__(256) void rmsnorm_in(
    const float* __restrict__ x, const float* __restrict__ w,
    unsigned short* __restrict__ h) {
  const int row = blockIdx.x;
  const float* xr = x + (size_t)row * 2048;
  const int base = threadIdx.x * 8;
  float4 v0 = *reinterpret_cast<const float4*>(xr + base);
  float4 v1 = *reinterpret_cast<const float4*>(xr + base + 4);
  float ss = v0.x*v0.x + v0.y*v0.y + v0.z*v0.z + v0.w*v0.w
           + v1.x*v1.x + v1.y*v1.y + v1.z*v1.z + v1.w*v1.w;
  __shared__ float red[4];
#pragma unroll
  for (int off = 32; off > 0; off >>= 1) ss += __shfl_xor(ss, off);
  if ((threadIdx.x & 63) == 0) red[threadIdx.x >> 6] = ss;
  __syncthreads();
  ss = red[0] + red[1] + red[2] + red[3];
  const float scale = rsqrtf(ss * (1.0f / 2048.0f) + 1e-5f);
  float vals[8] = {v0.x, v0.y, v0.z, v0.w, v1.x, v1.y, v1.z, v1.w};
  unsigned short o[8];
#pragma unroll
  for (int j = 0; j < 8; ++j) o[j] = f2b(vals[j] * scale * w[base + j]);
  ushort4 a, b;
  a.x = o[0]; a.y = o[1]; a.z = o[2]; a.w = o[3];
  b.x = o[4]; b.y = o[5]; b.z = o[6]; b.w = o[7];
  *reinterpret_cast<ushort4*>(h + (size_t)row * 2048 + base)     = a;
  *reinterpret_cast<ushort4*>(h + (size_t)row * 2048 + base + 4) = b;
}

// ---------------------------------------------------------------------------
// bf16 GEMM, C[M,N] = A[M,K] @ B[N,K]^T (+ optional residual), fp32 out.
// 128x128 tile, BK=32, 4 waves (2x2), each wave 64x64 via 4x4 x mfma 16x16x32.
// global_load_lds width-16 staging (m97 structure).
// ---------------------------------------------------------------------------
template<bool RES>
__global__ __launch_bounds__(256, 2) void gemm_bt(
    const unsigned short* __restrict__ A, const unsigned short* __restrict__ B,
    float* __restrict__ C, const float* __restrict__ res,
    int K, int Nc, int ldc) {
  __shared__ __align__(16) unsigned short As[128 * 32];
  __shared__ __align__(16) unsigned short Bs[128 * 32];
  const int tid  = threadIdx.x;
  const int m0   = blockIdx.y * 128;
  const int n0   = blockIdx.x * 128;
  const int wid  = tid >> 6;
  const int lane = tid & 63;
  const int wm   = (wid >> 1) * 64;
  const int wn   = (wid & 1) * 64;
  const int lrow = lane & 15;
  const int lk   = (lane >> 4) * 8;

  f32x4 acc[4][4] = {};

  const int ci0 = tid,        r0 = ci0 >> 2, c0 = (ci0 & 3) * 8;
  const int ci1 = tid + 256,  r1 = ci1 >> 2, c1 = (ci1 & 3) * 8;

  for (int k0 = 0; k0 < K; k0 += 32) {
    __builtin_amdgcn_global_load_lds(
        (const __attribute__((address_space(1))) void*)(A + (size_t)(m0 + r0) * K + k0 + c0),
        (__attribute__((address_space(3))) void*)(As + ci0 * 8), 16, 0, 0);
    __builtin_amdgcn_global_load_lds(
        (const __attribute__((address_space(1))) void*)(A + (size_t)(m0 + r1) * K + k0 + c1),
        (__attribute__((address_space(3))) void*)(As + ci1 * 8), 16, 0, 0);
    __builtin_amdgcn_global_load_lds(
        (const __attribute__((address_space(1))) void*)(B + (size_t)(n0 + r0) * K + k0 + c0),
        (__attribute__((address_space(3))) void*)(Bs + ci0 * 8), 16, 0, 0);
    __builtin_amdgcn_global_load_lds(
        (const __attribute__((address_space(1))) void*)(B + (size_t)(n0 + r1) * K + k0 + c1),
        (__attribute__((address_space(3))) void*)(Bs + ci1 * 8), 16, 0, 0);
    __syncthreads();   // compiler emits s_waitcnt vmcnt(0) before s_barrier

    bf16x8 af[4], bff[4];
#pragma unroll
    for (int m = 0; m < 4; ++m)
      af[m] = *reinterpret_cast<const bf16x8*>(&As[(wm + m * 16 + lrow) * 32 + lk]);
#pragma unroll
    for (int n = 0; n < 4; ++n)
      bff[n] = *reinterpret_cast<const bf16x8*>(&Bs[(wn + n * 16 + lrow) * 32 + lk]);
#pragma unroll
    for (int m = 0; m < 4; ++m)
#pragma unroll
      for (int n = 0; n < 4; ++n)
        acc[m][n] = __builtin_amdgcn_mfma_f32_16x16x32_bf16(af[m], bff[n], acc[m][n], 0, 0, 0);
    __syncthreads();
  }

  // C/D layout: col = lane&15, row = (lane>>4)*4 + reg  [m89/m91 verified]
#pragma unroll
  for (int m = 0; m < 4; ++m) {
#pragma unroll
    for (int n = 0; n < 4; ++n) {
      const int col = n0 + wn + n * 16 + lrow;
      if (col < Nc) {
#pragma unroll
        for (int v = 0; v < 4; ++v) {
          const int row = m0 + wm + m * 16 + (lane >> 4) * 4 + v;
          const size_t idx = (size_t)row * ldc + col;
          float val = acc[m][n][v];
          if (RES) val += res[idx];
          C[idx] = val;
        }
      }
    }
  }
}

// ---------------------------------------------------------------------------
// causal depthwise conv(K=4) + SiLU for xBC channels; softplus(dt+bias)
// proj row layout: [z 0..4095 | xBC 4096..8447 | dt 8448..8511]
// ---------------------------------------------------------------------------
__global__ __launch_bounds__(256) void conv_silu_dt(
    const float* __restrict__ proj, const float* __restrict__ conv_w,
    const float* __restrict__ conv_b, const float* __restrict__ dt_bias,
    float* __restrict__ xs, float* __restrict__ BC, float* __restrict__ dtc) {
  const int l = blockIdx.y;
  const int cch = blockIdx.x * 256 + threadIdx.x;
  if (cch < 4352) {
    float acc = conv_b[cch];
    const float4 w = *reinterpret_cast<const float4*>(conv_w + (size_t)cch * 4);
    const float wk[4] = {w.x, w.y, w.z, w.w};
    const float* pcol = proj + 4096 + cch;
#pragma unroll
    for (int k = 0; k < 4; ++k) {
      const int lr = l - 3 + k;
      if (lr >= 0) acc += pcol[(size_t)lr * 8512] * wk[k];
    }
    acc = acc / (1.0f + expf(-acc));       // silu
    if (cch < 4096) xs[(size_t)l * 4096 + cch] = acc;
    else            BC[(size_t)l * 256 + (cch - 4096)] = acc;
  } else if (cch < 4416) {
    const int hh = cch - 4352;
    const float v = proj[(size_t)l * 8512 + 8448 + hh] + dt_bias[hh];
    dtc[(size_t)l * 64 + hh] = (v > 20.0f) ? v : log1pf(expf(v));
  }
}

// ---------------------------------------------------------------------------
// per-(chunk,head) inclusive cumsum of dA = dt*A over the 256-long chunk
// ---------------------------------------------------------------------------
__global__ __launch_bounds__(256) void scan_dA(
    const float* __restrict__ dtc, const float* __restrict__ A_log,
    float* __restrict__ dAc, float* __restrict__ cdec) {
  const int bx = blockIdx.x;              // c*64 + h
  const int c = bx >> 6, h = bx & 63;
  const int l = threadIdx.x;
  __shared__ float buf[256];
  const float Ah = -expf(A_log[h]);
  buf[l] = dtc[(size_t)(c * 256 + l) * 64 + h] * Ah;
  __syncthreads();
  for (int off = 1; off < 256; off <<= 1) {
    const float t = (l >= off) ? buf[l - off] : 0.0f;
    __syncthreads();
    buf[l] += t;
    __syncthreads();
  }
  dAc[(size_t)bx * 256 + l] = buf[l];
  if (l == 255) cdec[bx] = expf(buf[255]);
}

// ---------------------------------------------------------------------------
// CB[c][l][s] = sum_n C[c,l,n] * B[c,s,n]   (G=1, shared across heads)
// one block per global row l (2048 blocks), thread = s
// ---------------------------------------------------------------------------
__global__ __launch_bounds__(256) void cb_k(const float* __restrict__ BC,
                                            float* __restrict__ CB) {
  const int gl = blockIdx.x;              // c*256 + l
  const int c = gl >> 8;
  const int s = threadIdx.x;
  __shared__ float Crow[128];
  if (threadIdx.x < 128) Crow[threadIdx.x] = BC[(size_t)gl * 256 + 128 + threadIdx.x];
  __syncthreads();
  const float* Br = BC + (size_t)(c * 256 + s) * 256;
  float acc = 0.0f;
#pragma unroll 4
  for (int n = 0; n < 128; ++n) acc += Crow[n] * Br[n];
  CB[(size_t)gl * 256 + s] = acc;
}

// ---------------------------------------------------------------------------
// intra-chunk: Y_diag + D*xs -> y (in-place over xs), and per-chunk states.
// one block per (chunk, head); xs tile [256][64] staged in LDS (64 KB).
// NOTE: y aliases xs (safe: block reads its xs slice into LDS before writes).
// ---------------------------------------------------------------------------
__global__ __launch_bounds__(256, 2) void ssd_intra(
    const float* xs, const float* __restrict__ BC,
    const float* __restrict__ dtc, const float* __restrict__ dAc,
    const float* __restrict__ CBp, const float* __restrict__ Dp,
    float* y, float* __restrict__ states) {
  const int bx = blockIdx.x;              // c*64 + h
  const int c = bx >> 6, h = bx & 63;
  __shared__ __align__(16) float xsL[256 * 64];
  __shared__ float dAL[256];
  __shared__ float dtL[256];
  __shared__ float wL[256];
  const int tid = threadIdx.x;
#pragma unroll 8
  for (int i = 0; i < 64; ++i) {
    const int idx = tid + i * 256;        // idx = s*64 + p
    xsL[idx] = xs[(size_t)(c * 256 + (idx >> 6)) * 4096 + h * 64 + (idx & 63)];
  }
  dAL[tid] = dAc[(size_t)bx * 256 + tid];
  dtL[tid] = dtc[(size_t)(c * 256 + tid) * 64 + h];
  __syncthreads();
  const float dAlast = dAL[255];
  wL[tid] = __expf(dAlast - dAL[tid]) * dtL[tid];
  __syncthreads();

  // ---- Y_diag: thread owns output row l = tid; s<=l triangular loop,
  //      all active lanes broadcast-read the same xsL row.
  const int l = tid;
  const float dAl = dAL[l];
  const float* CBrow = CBp + ((size_t)c * 256 + l) * 256;
  f32x4 yv[16] = {};
  for (int s = 0; s <= l; ++s) {
    const float mcoef = CBrow[s] * __expf(dAl - dAL[s]) * dtL[s];
    const f32x4* xr = reinterpret_cast<const f32x4*>(&xsL[s * 64]);
#pragma unroll
    for (int q = 0; q < 16; ++q) yv[q] += mcoef * xr[q];
  }
  const float Dh = Dp[h];
  float* yo = y + (size_t)(c * 256 + l) * 4096 + h * 64;
  const f32x4* xl = reinterpret_cast<const f32x4*>(&xsL[l * 64]);
#pragma unroll
  for (int q = 0; q < 16; ++q) {
    f32x4 o = yv[q] + Dh * xl[q];
    *reinterpret_cast<f32x4*>(yo + q * 4) = o;
  }

  // ---- states[c][h][n][p] = sum_l B[l,n]*w[l]*xs[l,p]
  const int n  = tid & 127;
  const int ph = tid >> 7;
  f32x4 st[8] = {};
  for (int s = 0; s < 256; ++s) {
    const float bw = BC[(size_t)(c * 256 + s) * 256 + n] * wL[s];
    const f32x4* xr = reinterpret_cast<const f32x4*>(&xsL[s * 64 + ph * 32]);
#pragma unroll
    for (int q = 0; q < 8; ++q) st[q] += bw * xr[q];
  }
  float* so = states + ((size_t)bx * 128 + n) * 64 + ph * 32;
#pragma unroll
  for (int q = 0; q < 8; ++q) *reinterpret_cast<f32x4*>(so + q * 4) = st[q];
}

// ---------------------------------------------------------------------------
// inter-chunk scan (8 sequential chunks), in-place: states[c] := prev_state[c]
// ---------------------------------------------------------------------------
__global__ void ssd_scan(float* __restrict__ states, const float* __restrict__ cdec) {
  const int i = blockIdx.x * 256 + threadIdx.x;   // < 64*8192
  const int h = i >> 13;
  const int r = i & 8191;
  float carry = 0.0f;
#pragma unroll
  for (int c = 0; c < 8; ++c) {
    const size_t idx = ((size_t)(c * 64 + h)) * 8192 + r;
    const float st = states[idx];
    states[idx] = carry;                           // emit state BEFORE chunk
    carry = carry * cdec[c * 64 + h] + st;
  }
}

// ---------------------------------------------------------------------------
// Y_off: y[l,h,p] += exp(dAc[l]) * sum_n C[l,n] * prev[h][n][p]
// ---------------------------------------------------------------------------
__global__ __launch_bounds__(256, 2) void ssd_off(
    const float* __restrict__ BC, const float* __restrict__ dAc,
    const float* __restrict__ prev, float* __restrict__ y) {
  const int bx = blockIdx.x;              // c*64 + h
  const int c = bx >> 6, h = bx & 63;
  __shared__ __align__(16) float pL[128 * 64];
  const int tid = threadIdx.x;
#pragma unroll 8
  for (int i = 0; i < 32; ++i) pL[tid + i * 256] = prev[(size_t)bx * 8192 + tid + i * 256];
  __syncthreads();
  const int l = tid;
  const float eA = __expf(dAc[(size_t)bx * 256 + l]);
  const float* Crow = BC + (size_t)(c * 256 + l) * 256 + 128;
  f32x4 acc[16] = {};
  for (int n = 0; n < 128; ++n) {
    const float cl = Crow[n];
    const f32x4* pr = reinterpret_cast<const f32x4*>(&pL[n * 64]);
#pragma unroll
    for (int q = 0; q < 16; ++q) acc[q] += cl * pr[q];
  }
  float* yo = y + (size_t)(c * 256 + l) * 4096 + h * 64;
#pragma unroll
  for (int q = 0; q < 16; ++q) {
    f32x4 cur = *reinterpret_cast<const f32x4*>(yo + q * 4);
    cur += eA * acc[q];
    *reinterpret_cast<f32x4*>(yo + q * 4) = cur;
  }
}

// ---------------------------------------------------------------------------
// gated RMSNorm: y2 = rmsnorm(y * silu(z)) * norm_w  -> bf16
// ---------------------------------------------------------------------------
__global__ __launch_bounds__(256) void gated_rmsnorm(
    const float* __restrict__ y, const float* __restrict__ proj,
    const float* __restrict__ nw, unsigned short* __restrict__ y2) {
  const int row = blockIdx.x;
  const float* yr = y + (size_t)row * 4096;
  const float* zr = proj + (size_t)row * 8512;    // z = cols 0..4095
  const int base = threadIdx.x * 16;
  float g[16];
  float ss = 0.0f;
#pragma unroll
  for (int j = 0; j < 16; j += 4) {
    const float4 yv = *reinterpret_cast<const float4*>(yr + base + j);
    const float4 zv = *reinterpret_cast<const float4*>(zr + base + j);
    const float a0 = yv.x * (zv.x / (1.0f + expf(-zv.x)));
    const float a1 = yv.y * (zv.y / (1.0f + expf(-zv.y)));
    const float a2 = yv.z * (zv.z / (1.0f + expf(-zv.z)));
    const float a3 = yv.w * (zv.w / (1.0f + expf(-zv.w)));
    g[j] = a0; g[j+1] = a1; g[j+2] = a2; g[j+3] = a3;
    ss += a0*a0 + a1*a1 + a2*a2 + a3*a3;
  }
  __shared__ float red[4];
#pragma unroll
  for (int off = 32; off > 0; off >>= 1) ss += __shfl_xor(ss, off);
  if ((threadIdx.x & 63) == 0) red[threadIdx.x >> 6] = ss;
  __syncthreads();
  ss = red[0] + red[1] + red[2] + red[3];
  const float scale = rsqrtf(ss * (1.0f / 4096.0f) + 1e-5f);
#pragma unroll
  for (int j = 0; j < 16; j += 4) {
    ushort4 o;
    o.x = f2b(g[j]   * scale * nw[base + j]);
    o.y = f2b(g[j+1] * scale * nw[base + j + 1]);
    o.z = f2b(g[j+2] * scale * nw[base + j + 2]);
    o.w = f2b(g[j+3] * scale * nw[base + j + 3]);
    *reinterpret_cast<ushort4*>(y2 + (size_t)row * 4096 + base + j) = o;
  }
}

// ---------------------------------------------------------------------------
extern "C" void kernel_launch(void* const* d_in, const int* in_sizes, int n_in,
                              void* d_out, int out_size, void* d_ws, size_t ws_size,
                              hipStream_t stream) {
  const float* x       = (const float*)d_in[0];
  const float* rms_w   = (const float*)d_in[1];
  const float* W_in    = (const float*)d_in[2];
  const float* conv_w  = (const float*)d_in[3];
  const float* conv_b  = (const float*)d_in[4];
  const float* dt_bias = (const float*)d_in[5];
  const float* A_log   = (const float*)d_in[6];
  const float* Dp      = (const float*)d_in[7];
  const float* norm_w  = (const float*)d_in[8];
  const float* W_out   = (const float*)d_in[9];
  float* out = (float*)d_out;

  char* ws = (char*)d_ws;
  size_t off = 0;
  auto alloc = [&](size_t bytes) {
    void* p = ws + off;
    off += (bytes + 255) & ~(size_t)255;
    return p;
  };
  unsigned short* Wb_in  = (unsigned short*)alloc((size_t)8576 * 2048 * 2); // padded rows
  unsigned short* Wb_out = (unsigned short*)alloc((size_t)2048 * 4096 * 2);
  unsigned short* hbuf   = (unsigned short*)alloc((size_t)2048 * 2048 * 2);
  float* proj   = (float*)alloc((size_t)2048 * 8512 * 4);
  float* xsbuf  = (float*)alloc((size_t)2048 * 4096 * 4);   // xs, then y (in-place)
  float* BCbuf  = (float*)alloc((size_t)2048 * 256 * 4);
  float* dtcbuf = (float*)alloc((size_t)2048 * 64 * 4);
  float* dAcbuf = (float*)alloc((size_t)512 * 256 * 4);
  float* cdec   = (float*)alloc((size_t)512 * 4);
  float* CBbuf  = (float*)alloc((size_t)8 * 256 * 256 * 4);
  float* states = (float*)alloc((size_t)512 * 128 * 64 * 4);
  unsigned short* y2 = Wb_in;   // reuse: Wb_in dead after in_proj GEMM

  (void)in_sizes; (void)n_in; (void)out_size; (void)ws_size;

  // weight conversion (every call; no caching allowed)
  f32_to_bf16_pad<<<(8576 * 2048 / 4 + 255) / 256, 256, 0, stream>>>(
      W_in, Wb_in, (long)8512 * 2048, (long)8576 * 2048);
  f32_to_bf16_pad<<<(2048 * 4096 / 4 + 255) / 256, 256, 0, stream>>>(
      W_out, Wb_out, (long)2048 * 4096, (long)2048 * 4096);

  // 1. input RMSNorm -> bf16
  rmsnorm_in<<<2048, 256, 0, stream>>>(x, rms_w, hbuf);

  // 2. in_proj: proj[2048,8512] = h @ W_in^T
  gemm_bt<false><<<dim3(67, 16), 256, 0, stream>>>(hbuf, Wb_in, proj, nullptr,
                                                   2048, 8512, 8512);

  // 3. conv + SiLU + softplus(dt)
  conv_silu_dt<<<dim3(18, 2048), 256, 0, stream>>>(proj, conv_w, conv_b, dt_bias,
                                                   xsbuf, BCbuf, dtcbuf);

  // 4. per-(chunk,head) cumsum of dt*A; chunk decay
  scan_dA<<<512, 256, 0, stream>>>(dtcbuf, A_log, dAcbuf, cdec);

  // 5. CB = C @ B^T per chunk
  cb_k<<<2048, 256, 0, stream>>>(BCbuf, CBbuf);

  // 6. intra-chunk Y_diag + D*xs (y in-place over xs) and chunk states
  ssd_intra<<<512, 256, 0, stream>>>(xsbuf, BCbuf, dtcbuf, dAcbuf, CBbuf, Dp,
                                     xsbuf, states);

  // 7. inter-chunk recurrence (in-place: states -> prev_states)
  ssd_scan<<<2048, 256, 0, stream>>>(states, cdec);

  // 8. Y_off accumulate into y
  ssd_off<<<512, 256, 0, stream>>>(BCbuf, dAcbuf, states, xsbuf);

  // 9. gated RMSNorm -> bf16
  gated_rmsnorm<<<2048, 256, 0, stream>>>(xsbuf, proj, norm_w, y2);

  // 10. out_proj + residual -> d_out
  gemm_bt<true><<<dim3(16, 16), 256, 0, stream>>>(y2, Wb_out, out, x,
                                                  4096, 2048, 2048);
}

// Round 3
// 485.147 us; speedup vs baseline: 1.0994x; 1.0994x over previous
//
#include <hip/hip_runtime.h>
#include <stdint.h>

// ---------------------------------------------------------------------------
// FalconMamba2 SSM decoder layer, MI355X (gfx950) — round 3
// Round-2 structure with the gemm_bt BK=64 staging bug fixed (4 iters, not 2).
// ---------------------------------------------------------------------------

typedef __bf16 bf16x8 __attribute__((ext_vector_type(8)));
typedef float  f32x4  __attribute__((ext_vector_type(4)));

#define DEVFN __device__ __forceinline__

DEVFN unsigned short f2b(float f) {
  uint32_t u = __builtin_bit_cast(uint32_t, f);
  u += 0x7fffu + ((u >> 16) & 1u);          // round-to-nearest-even
  return (unsigned short)(u >> 16);
}

// bijective XCD swizzle (m204) + GROUP-major supertiling
DEVFN void tile_map(int bid, int nwg, int nm, int nn, int grp, int& mt, int& nt) {
  const int q = nwg >> 3, r = nwg & 7;
  const int xcd = bid & 7, lid = bid >> 3;
  const int wg = (xcd < r ? xcd * (q + 1) : r * (q + 1) + (xcd - r) * q) + lid;
  const int per = grp * nn;
  const int g = wg / per;
  const int rem = wg - g * per;
  const int lim = nm - g * grp;
  const int gm = lim < grp ? lim : grp;
  mt = g * grp + rem % gm;
  nt = rem / gm;
}

// ---------------------------------------------------------------------------
// fp32 -> bf16 conversion with zero-padding tail (pad rows for GEMM tiles)
// ---------------------------------------------------------------------------
__global__ void f32_to_bf16_pad(const float* __restrict__ src,
                                unsigned short* __restrict__ dst,
                                long srcElems, long dstElems) {
  const long i = ((long)blockIdx.x * 256 + threadIdx.x) * 4;
  if (i >= dstElems) return;
  ushort4 o;
  if (i < srcElems) {
    float4 v = *reinterpret_cast<const float4*>(src + i);
    o.x = f2b(v.x); o.y = f2b(v.y); o.z = f2b(v.z); o.w = f2b(v.w);
  } else {
    o.x = 0; o.y = 0; o.z = 0; o.w = 0;
  }
  *reinterpret_cast<ushort4*>(dst + i) = o;
}

// ---------------------------------------------------------------------------
// input RMSNorm: x[2048][2048] f32 -> h bf16
// ---------------------------------------------------------------------------
__global__ __launch_bounds__(256) void rmsnorm_in(
    const float* __restrict__ x, const float* __restrict__ w,
    unsigned short* __restrict__ h) {
  const int row = blockIdx.x;
  const float* xr = x + (size_t)row * 2048;
  const int base = threadIdx.x * 8;
  float4 v0 = *reinterpret_cast<const float4*>(xr + base);
  float4 v1 = *reinterpret_cast<const float4*>(xr + base + 4);
  float ss = v0.x*v0.x + v0.y*v0.y + v0.z*v0.z + v0.w*v0.w
           + v1.x*v1.x + v1.y*v1.y + v1.z*v1.z + v1.w*v1.w;
  __shared__ float red[4];
#pragma unroll
  for (int off = 32; off > 0; off >>= 1) ss += __shfl_xor(ss, off);
  if ((threadIdx.x & 63) == 0) red[threadIdx.x >> 6] = ss;
  __syncthreads();
  ss = red[0] + red[1] + red[2] + red[3];
  const float scale = rsqrtf(ss * (1.0f / 2048.0f) + 1e-5f);
  float vals[8] = {v0.x, v0.y, v0.z, v0.w, v1.x, v1.y, v1.z, v1.w};
  unsigned short o[8];
#pragma unroll
  for (int j = 0; j < 8; ++j) o[j] = f2b(vals[j] * scale * w[base + j]);
  ushort4 a, b;
  a.x = o[0]; a.y = o[1]; a.z = o[2]; a.w = o[3];
  b.x = o[4]; b.y = o[5]; b.z = o[6]; b.w = o[7];
  *reinterpret_cast<ushort4*>(h + (size_t)row * 2048 + base)     = a;
  *reinterpret_cast<ushort4*>(h + (size_t)row * 2048 + base + 4) = b;
}

// ---------------------------------------------------------------------------
// bf16 GEMM, C[M,N] = A[M,K] @ B[N,K]^T, fp32 out. 128x128 tile, BK=64,
// 4 waves (2x2), each wave 64x64 via 4x4x2 mfma 16x16x32. 1D swizzled grid.
// Staging: 128x64 tile = 1024 16B chunks per operand -> 4 iters x 256 thr.
// ---------------------------------------------------------------------------
template<bool RES>
__global__ __launch_bounds__(256, 2) void gemm_bt(
    const unsigned short* __restrict__ A, const unsigned short* __restrict__ B,
    float* __restrict__ C, const float* __restrict__ res,
    int K, int Nc, int ldc, int nm, int nn, int grp) {
  __shared__ __align__(16) unsigned short As[128 * 64];
  __shared__ __align__(16) unsigned short Bs[128 * 64];
  int mt, nt;
  tile_map(blockIdx.x, nm * nn, nm, nn, grp, mt, nt);
  const int m0 = mt * 128;
  const int n0 = nt * 128;
  const int tid  = threadIdx.x;
  const int wid  = tid >> 6;
  const int lane = tid & 63;
  const int wm   = (wid >> 1) * 64;
  const int wn   = (wid & 1) * 64;
  const int lrow = lane & 15;
  const int lk   = (lane >> 4) * 8;

  f32x4 acc[4][4] = {};

  for (int k0 = 0; k0 < K; k0 += 64) {
#pragma unroll
    for (int i = 0; i < 4; ++i) {
      const int ci = tid + i * 256;             // [0, 1024)
      const int r = ci >> 3, cc = (ci & 7) * 8;
      __builtin_amdgcn_global_load_lds(
          (const __attribute__((address_space(1))) void*)(A + (size_t)(m0 + r) * K + k0 + cc),
          (__attribute__((address_space(3))) void*)(As + ci * 8), 16, 0, 0);
      __builtin_amdgcn_global_load_lds(
          (const __attribute__((address_space(1))) void*)(B + (size_t)(n0 + r) * K + k0 + cc),
          (__attribute__((address_space(3))) void*)(Bs + ci * 8), 16, 0, 0);
    }
    __syncthreads();   // compiler emits s_waitcnt vmcnt(0) before s_barrier

    bf16x8 af[4][2], bf[4][2];
#pragma unroll
    for (int m = 0; m < 4; ++m)
#pragma unroll
      for (int kk = 0; kk < 2; ++kk)
        af[m][kk] = *reinterpret_cast<const bf16x8*>(&As[(wm + m * 16 + lrow) * 64 + kk * 32 + lk]);
#pragma unroll
    for (int n = 0; n < 4; ++n)
#pragma unroll
      for (int kk = 0; kk < 2; ++kk)
        bf[n][kk] = *reinterpret_cast<const bf16x8*>(&Bs[(wn + n * 16 + lrow) * 64 + kk * 32 + lk]);
#pragma unroll
    for (int kk = 0; kk < 2; ++kk)
#pragma unroll
      for (int m = 0; m < 4; ++m)
#pragma unroll
        for (int n = 0; n < 4; ++n)
          acc[m][n] = __builtin_amdgcn_mfma_f32_16x16x32_bf16(af[m][kk], bf[n][kk], acc[m][n], 0, 0, 0);
    __syncthreads();
  }

  // C/D layout: col = lane&15, row = (lane>>4)*4 + reg  [m89/m91 verified]
#pragma unroll
  for (int m = 0; m < 4; ++m) {
#pragma unroll
    for (int n = 0; n < 4; ++n) {
      const int col = n0 + wn + n * 16 + lrow;
      if (col < Nc) {
#pragma unroll
        for (int v = 0; v < 4; ++v) {
          const int row = m0 + wm + m * 16 + (lane >> 4) * 4 + v;
          const size_t idx = (size_t)row * ldc + col;
          float val = acc[m][n][v];
          if (RES) val += res[idx];
          C[idx] = val;
        }
      }
    }
  }
}

// ---------------------------------------------------------------------------
// bf16 GEMM variant: 64x128 tile, BK=64, 4 waves (2x2), wave 32x64 (acc 2x4).
// 512 blocks for M=2048,N=2048 -> 2 blocks/CU for latency hiding.
// ---------------------------------------------------------------------------
template<bool RES>
__global__ __launch_bounds__(256, 2) void gemm_bt64(
    const unsigned short* __restrict__ A, const unsigned short* __restrict__ B,
    float* __restrict__ C, const float* __restrict__ res,
    int K, int Nc, int ldc, int nm, int nn, int grp) {
  __shared__ __align__(16) unsigned short As[64 * 64];
  __shared__ __align__(16) unsigned short Bs[128 * 64];
  int mt, nt;
  tile_map(blockIdx.x, nm * nn, nm, nn, grp, mt, nt);
  const int m0 = mt * 64;
  const int n0 = nt * 128;
  const int tid  = threadIdx.x;
  const int wid  = tid >> 6;
  const int lane = tid & 63;
  const int wm   = (wid >> 1) * 32;
  const int wn   = (wid & 1) * 64;
  const int lrow = lane & 15;
  const int lk   = (lane >> 4) * 8;

  f32x4 acc[2][4] = {};

  for (int k0 = 0; k0 < K; k0 += 64) {
#pragma unroll
    for (int i = 0; i < 2; ++i) {          // A: 64x64 = 512 chunks
      const int ci = tid + i * 256;
      const int r = ci >> 3, cc = (ci & 7) * 8;
      __builtin_amdgcn_global_load_lds(
          (const __attribute__((address_space(1))) void*)(A + (size_t)(m0 + r) * K + k0 + cc),
          (__attribute__((address_space(3))) void*)(As + ci * 8), 16, 0, 0);
    }
#pragma unroll
    for (int i = 0; i < 4; ++i) {          // B: 128x64 = 1024 chunks
      const int ci = tid + i * 256;
      const int r = ci >> 3, cc = (ci & 7) * 8;
      __builtin_amdgcn_global_load_lds(
          (const __attribute__((address_space(1))) void*)(B + (size_t)(n0 + r) * K + k0 + cc),
          (__attribute__((address_space(3))) void*)(Bs + ci * 8), 16, 0, 0);
    }
    __syncthreads();

    bf16x8 af[2][2], bf[4][2];
#pragma unroll
    for (int m = 0; m < 2; ++m)
#pragma unroll
      for (int kk = 0; kk < 2; ++kk)
        af[m][kk] = *reinterpret_cast<const bf16x8*>(&As[(wm + m * 16 + lrow) * 64 + kk * 32 + lk]);
#pragma unroll
    for (int n = 0; n < 4; ++n)
#pragma unroll
      for (int kk = 0; kk < 2; ++kk)
        bf[n][kk] = *reinterpret_cast<const bf16x8*>(&Bs[(wn + n * 16 + lrow) * 64 + kk * 32 + lk]);
#pragma unroll
    for (int kk = 0; kk < 2; ++kk)
#pragma unroll
      for (int m = 0; m < 2; ++m)
#pragma unroll
        for (int n = 0; n < 4; ++n)
          acc[m][n] = __builtin_amdgcn_mfma_f32_16x16x32_bf16(af[m][kk], bf[n][kk], acc[m][n], 0, 0, 0);
    __syncthreads();
  }

#pragma unroll
  for (int m = 0; m < 2; ++m) {
#pragma unroll
    for (int n = 0; n < 4; ++n) {
      const int col = n0 + wn + n * 16 + lrow;
      if (col < Nc) {
#pragma unroll
        for (int v = 0; v < 4; ++v) {
          const int row = m0 + wm + m * 16 + (lane >> 4) * 4 + v;
          const size_t idx = (size_t)row * ldc + col;
          float val = acc[m][n][v];
          if (RES) val += res[idx];
          C[idx] = val;
        }
      }
    }
  }
}

// ---------------------------------------------------------------------------
// causal depthwise conv(K=4) + SiLU; softplus(dt+bias). 16 l per thread.
// proj row layout: [z 0..4095 | xBC 4096..8447 | dt 8448..8511]
// Also emits CT[c][n][l] (transposed C) for ssd_off.
// ---------------------------------------------------------------------------
__global__ __launch_bounds__(256) void conv_silu_dt(
    const float* __restrict__ proj, const float* __restrict__ conv_w,
    const float* __restrict__ conv_b, const float* __restrict__ dt_bias,
    float* __restrict__ xs, float* __restrict__ BC, float* __restrict__ CT,
    float* __restrict__ dtc) {
  const int cch = blockIdx.x * 256 + threadIdx.x;
  const int l0 = blockIdx.y * 16;
  if (cch < 4352) {
    const float4 w = *reinterpret_cast<const float4*>(conv_w + (size_t)cch * 4);
    const float b = conv_b[cch];
    const float* pcol = proj + 4096 + cch;
    float w0, w1, w2;
    w0 = (l0 >= 3) ? pcol[(size_t)(l0 - 3) * 8512] : 0.0f;
    w1 = (l0 >= 2) ? pcol[(size_t)(l0 - 2) * 8512] : 0.0f;
    w2 = (l0 >= 1) ? pcol[(size_t)(l0 - 1) * 8512] : 0.0f;
#pragma unroll
    for (int i = 0; i < 16; ++i) {
      const int l = l0 + i;
      const float cur = pcol[(size_t)l * 8512];
      float acc = b + w0 * w.x + w1 * w.y + w2 * w.z + cur * w.w;
      w0 = w1; w1 = w2; w2 = cur;
      acc = acc / (1.0f + __expf(-acc));   // silu
      if (cch < 4096) {
        xs[(size_t)l * 4096 + cch] = acc;
      } else {
        BC[(size_t)l * 256 + (cch - 4096)] = acc;
        if (cch >= 4224) {
          const int n = cch - 4224;
          const int c = l >> 8;
          CT[((size_t)(c * 128) + n) * 256 + (l & 255)] = acc;
        }
      }
    }
  } else if (cch < 4416) {
    const int hh = cch - 4352;
    const float bias = dt_bias[hh];
#pragma unroll
    for (int i = 0; i < 16; ++i) {
      const int l = l0 + i;
      const float v = proj[(size_t)l * 8512 + 8448 + hh] + bias;
      dtc[(size_t)l * 64 + hh] = (v > 20.0f) ? v : log1pf(expf(v));
    }
  }
}

// ---------------------------------------------------------------------------
// per-(chunk,head) inclusive cumsum of dA = dt*A over the 256-long chunk
// ---------------------------------------------------------------------------
__global__ __launch_bounds__(256) void scan_dA(
    const float* __restrict__ dtc, const float* __restrict__ A_log,
    float* __restrict__ dAc, float* __restrict__ cdec) {
  const int bx = blockIdx.x;              // c*64 + h
  const int c = bx >> 6, h = bx & 63;
  const int l = threadIdx.x;
  __shared__ float buf[256];
  const float Ah = -expf(A_log[h]);
  buf[l] = dtc[(size_t)(c * 256 + l) * 64 + h] * Ah;
  __syncthreads();
  for (int off = 1; off < 256; off <<= 1) {
    const float t = (l >= off) ? buf[l - off] : 0.0f;
    __syncthreads();
    buf[l] += t;
    __syncthreads();
  }
  dAc[(size_t)bx * 256 + l] = buf[l];
  if (l == 255) cdec[bx] = expf(buf[255]);
}

// ---------------------------------------------------------------------------
// CBT[c][s][l] = sum_n C[c,l,n] * B[c,s,n]  (transposed so Y_diag reads
// lane-coalesced). One block per (c,l); thread = s.
// ---------------------------------------------------------------------------
__global__ __launch_bounds__(256) void cb_k(const float* __restrict__ BC,
                                            float* __restrict__ CBT) {
  const int gl = blockIdx.x;              // c*256 + l
  const int c = gl >> 8, l = gl & 255;
  const int s = threadIdx.x;
  __shared__ float Crow[128];
  if (threadIdx.x < 128) Crow[threadIdx.x] = BC[(size_t)gl * 256 + 128 + threadIdx.x];
  __syncthreads();
  const float* Br = BC + (size_t)(c * 256 + s) * 256;
  float acc = 0.0f;
#pragma unroll 4
  for (int n = 0; n < 128; ++n) acc += Crow[n] * Br[n];
  CBT[((size_t)(c * 256) + s) * 256 + l] = acc;
}

// ---------------------------------------------------------------------------
// intra-chunk: Y_diag + D*xs -> y (in-place over xs), and per-chunk states.
// one block per (chunk, head); xs tile [256][64] staged in LDS (64 KB).
// ---------------------------------------------------------------------------
__global__ __launch_bounds__(256, 2) void ssd_intra(
    const float* xs, const float* __restrict__ BC,
    const float* __restrict__ dtc, const float* __restrict__ dAc,
    const float* __restrict__ CBT, const float* __restrict__ Dp,
    float* y, float* __restrict__ states) {
  const int bx = blockIdx.x;              // c*64 + h
  const int c = bx >> 6, h = bx & 63;
  __shared__ __align__(16) float xsL[256 * 64];
  __shared__ float dAL[256];
  __shared__ float dtL[256];
  __shared__ float wL[256];
  const int tid = threadIdx.x;
#pragma unroll 8
  for (int i = 0; i < 64; ++i) {
    const int idx = tid + i * 256;        // idx = s*64 + p
    xsL[idx] = xs[(size_t)(c * 256 + (idx >> 6)) * 4096 + h * 64 + (idx & 63)];
  }
  dAL[tid] = dAc[(size_t)bx * 256 + tid];
  dtL[tid] = dtc[(size_t)(c * 256 + tid) * 64 + h];
  __syncthreads();
  const float dAlast = dAL[255];
  wL[tid] = __expf(dAlast - dAL[tid]) * dtL[tid];
  __syncthreads();

  // ---- Y_diag: thread owns output row l = tid; CBT read is lane-coalesced.
  const int l = tid;
  const float dAl = dAL[l];
  const float* CBcol = CBT + (size_t)c * 65536 + l;   // + s*256
  f32x4 yv[16] = {};
  for (int s = 0; s <= l; ++s) {
    const float mcoef = CBcol[(size_t)s * 256] * __expf(dAl - dAL[s]) * dtL[s];
    const f32x4* xr = reinterpret_cast<const f32x4*>(&xsL[s * 64]);
#pragma unroll
    for (int q = 0; q < 16; ++q) yv[q] += mcoef * xr[q];
  }
  const float Dh = Dp[h];
  float* yo = y + (size_t)(c * 256 + l) * 4096 + h * 64;
  const f32x4* xl = reinterpret_cast<const f32x4*>(&xsL[l * 64]);
#pragma unroll
  for (int q = 0; q < 16; ++q) {
    f32x4 o = yv[q] + Dh * xl[q];
    *reinterpret_cast<f32x4*>(yo + q * 4) = o;
  }

  // ---- states[c][h][n][p] = sum_l B[l,n]*w[l]*xs[l,p]
  const int n  = tid & 127;
  const int ph = tid >> 7;
  f32x4 st[8] = {};
  for (int s = 0; s < 256; ++s) {
    const float bw = BC[(size_t)(c * 256 + s) * 256 + n] * wL[s];
    const f32x4* xr = reinterpret_cast<const f32x4*>(&xsL[s * 64 + ph * 32]);
#pragma unroll
    for (int q = 0; q < 8; ++q) st[q] += bw * xr[q];
  }
  float* so = states + ((size_t)bx * 128 + n) * 64 + ph * 32;
#pragma unroll
  for (int q = 0; q < 8; ++q) *reinterpret_cast<f32x4*>(so + q * 4) = st[q];
}

// ---------------------------------------------------------------------------
// inter-chunk scan (8 sequential chunks), in-place: states[c] := prev_state[c]
// ---------------------------------------------------------------------------
__global__ void ssd_scan(float* __restrict__ states, const float* __restrict__ cdec) {
  const int i = blockIdx.x * 256 + threadIdx.x;   // < 64*8192
  const int h = i >> 13;
  const int r = i & 8191;
  float carry = 0.0f;
#pragma unroll
  for (int c = 0; c < 8; ++c) {
    const size_t idx = ((size_t)(c * 64 + h)) * 8192 + r;
    const float st = states[idx];
    states[idx] = carry;                           // emit state BEFORE chunk
    carry = carry * cdec[c * 64 + h] + st;
  }
}

// ---------------------------------------------------------------------------
// Y_off: y[l,h,p] += exp(dAc[l]) * sum_n C[l,n] * prev[h][n][p]
// CT read is lane-coalesced.
// ---------------------------------------------------------------------------
__global__ __launch_bounds__(256, 2) void ssd_off(
    const float* __restrict__ CT, const float* __restrict__ dAc,
    const float* __restrict__ prev, float* __restrict__ y) {
  const int bx = blockIdx.x;              // c*64 + h
  const int c = bx >> 6, h = bx & 63;
  __shared__ __align__(16) float pL[128 * 64];
  const int tid = threadIdx.x;
#pragma unroll 8
  for (int i = 0; i < 32; ++i) pL[tid + i * 256] = prev[(size_t)bx * 8192 + tid + i * 256];
  __syncthreads();
  const int l = tid;
  const float eA = __expf(dAc[(size_t)bx * 256 + l]);
  const float* Ccol = CT + (size_t)(c * 128) * 256 + l;   // + n*256
  f32x4 acc[16] = {};
  for (int n = 0; n < 128; ++n) {
    const float cl = Ccol[(size_t)n * 256];
    const f32x4* pr = reinterpret_cast<const f32x4*>(&pL[n * 64]);
#pragma unroll
    for (int q = 0; q < 16; ++q) acc[q] += cl * pr[q];
  }
  float* yo = y + (size_t)(c * 256 + l) * 4096 + h * 64;
#pragma unroll
  for (int q = 0; q < 16; ++q) {
    f32x4 cur = *reinterpret_cast<const f32x4*>(yo + q * 4);
    cur += eA * acc[q];
    *reinterpret_cast<f32x4*>(yo + q * 4) = cur;
  }
}

// ---------------------------------------------------------------------------
// gated RMSNorm: y2 = rmsnorm(y * silu(z)) * norm_w  -> bf16
// ---------------------------------------------------------------------------
__global__ __launch_bounds__(256) void gated_rmsnorm(
    const float* __restrict__ y, const float* __restrict__ proj,
    const float* __restrict__ nw, unsigned short* __restrict__ y2) {
  const int row = blockIdx.x;
  const float* yr = y + (size_t)row * 4096;
  const float* zr = proj + (size_t)row * 8512;    // z = cols 0..4095
  const int base = threadIdx.x * 16;
  float g[16];
  float ss = 0.0f;
#pragma unroll
  for (int j = 0; j < 16; j += 4) {
    const float4 yv = *reinterpret_cast<const float4*>(yr + base + j);
    const float4 zv = *reinterpret_cast<const float4*>(zr + base + j);
    const float a0 = yv.x * (zv.x / (1.0f + expf(-zv.x)));
    const float a1 = yv.y * (zv.y / (1.0f + expf(-zv.y)));
    const float a2 = yv.z * (zv.z / (1.0f + expf(-zv.z)));
    const float a3 = yv.w * (zv.w / (1.0f + expf(-zv.w)));
    g[j] = a0; g[j+1] = a1; g[j+2] = a2; g[j+3] = a3;
    ss += a0*a0 + a1*a1 + a2*a2 + a3*a3;
  }
  __shared__ float red[4];
#pragma unroll
  for (int off = 32; off > 0; off >>= 1) ss += __shfl_xor(ss, off);
  if ((threadIdx.x & 63) == 0) red[threadIdx.x >> 6] = ss;
  __syncthreads();
  ss = red[0] + red[1] + red[2] + red[3];
  const float scale = rsqrtf(ss * (1.0f / 4096.0f) + 1e-5f);
#pragma unroll
  for (int j = 0; j < 16; j += 4) {
    ushort4 o;
    o.x = f2b(g[j]   * scale * nw[base + j]);
    o.y = f2b(g[j+1] * scale * nw[base + j + 1]);
    o.z = f2b(g[j+2] * scale * nw[base + j + 2]);
    o.w = f2b(g[j+3] * scale * nw[base + j + 3]);
    *reinterpret_cast<ushort4*>(y2 + (size_t)row * 4096 + base + j) = o;
  }
}

// ---------------------------------------------------------------------------
extern "C" void kernel_launch(void* const* d_in, const int* in_sizes, int n_in,
                              void* d_out, int out_size, void* d_ws, size_t ws_size,
                              hipStream_t stream) {
  const float* x       = (const float*)d_in[0];
  const float* rms_w   = (const float*)d_in[1];
  const float* W_in    = (const float*)d_in[2];
  const float* conv_w  = (const float*)d_in[3];
  const float* conv_b  = (const float*)d_in[4];
  const float* dt_bias = (const float*)d_in[5];
  const float* A_log   = (const float*)d_in[6];
  const float* Dp      = (const float*)d_in[7];
  const float* norm_w  = (const float*)d_in[8];
  const float* W_out   = (const float*)d_in[9];
  float* out = (float*)d_out;

  char* ws = (char*)d_ws;
  size_t off = 0;
  auto alloc = [&](size_t bytes) {
    void* p = ws + off;
    off += (bytes + 255) & ~(size_t)255;
    return p;
  };
  unsigned short* Wb_in  = (unsigned short*)alloc((size_t)8576 * 2048 * 2); // padded rows
  unsigned short* Wb_out = (unsigned short*)alloc((size_t)2048 * 4096 * 2);
  unsigned short* hbuf   = (unsigned short*)alloc((size_t)2048 * 2048 * 2);
  float* proj   = (float*)alloc((size_t)2048 * 8512 * 4);
  float* xsbuf  = (float*)alloc((size_t)2048 * 4096 * 4);   // xs, then y (in-place)
  float* BCbuf  = (float*)alloc((size_t)2048 * 256 * 4);
  float* CTbuf  = (float*)alloc((size_t)8 * 128 * 256 * 4);
  float* dtcbuf = (float*)alloc((size_t)2048 * 64 * 4);
  float* dAcbuf = (float*)alloc((size_t)512 * 256 * 4);
  float* cdec   = (float*)alloc((size_t)512 * 4);
  float* CBTbuf = (float*)alloc((size_t)8 * 256 * 256 * 4);
  float* states = (float*)alloc((size_t)512 * 128 * 64 * 4);
  unsigned short* y2 = Wb_in;   // reuse: Wb_in dead after in_proj GEMM

  (void)in_sizes; (void)n_in; (void)out_size; (void)ws_size;

  // weight conversion (every call; no caching allowed)
  f32_to_bf16_pad<<<(8576 * 2048 / 4 + 255) / 256, 256, 0, stream>>>(
      W_in, Wb_in, (long)8512 * 2048, (long)8576 * 2048);
  f32_to_bf16_pad<<<(2048 * 4096 / 4 + 255) / 256, 256, 0, stream>>>(
      W_out, Wb_out, (long)2048 * 4096, (long)2048 * 4096);

  // 1. input RMSNorm -> bf16
  rmsnorm_in<<<2048, 256, 0, stream>>>(x, rms_w, hbuf);

  // 2. in_proj: proj[2048,8512] = h @ W_in^T  (16 m-tiles x 67 n-tiles)
  gemm_bt<false><<<16 * 67, 256, 0, stream>>>(hbuf, Wb_in, proj, nullptr,
                                              2048, 8512, 8512, 16, 67, 4);

  // 3. conv + SiLU + softplus(dt); emits BC and transposed CT
  conv_silu_dt<<<dim3(18, 128), 256, 0, stream>>>(proj, conv_w, conv_b, dt_bias,
                                                  xsbuf, BCbuf, CTbuf, dtcbuf);

  // 4. per-(chunk,head) cumsum of dt*A; chunk decay
  scan_dA<<<512, 256, 0, stream>>>(dtcbuf, A_log, dAcbuf, cdec);

  // 5. CBT = (C @ B^T)^T per chunk
  cb_k<<<2048, 256, 0, stream>>>(BCbuf, CBTbuf);

  // 6. intra-chunk Y_diag + D*xs (y in-place over xs) and chunk states
  ssd_intra<<<512, 256, 0, stream>>>(xsbuf, BCbuf, dtcbuf, dAcbuf, CBTbuf, Dp,
                                     xsbuf, states);

  // 7. inter-chunk recurrence (in-place: states -> prev_states)
  ssd_scan<<<2048, 256, 0, stream>>>(states, cdec);

  // 8. Y_off accumulate into y
  ssd_off<<<512, 256, 0, stream>>>(CTbuf, dAcbuf, states, xsbuf);

  // 9. gated RMSNorm -> bf16
  gated_rmsnorm<<<2048, 256, 0, stream>>>(xsbuf, proj, norm_w, y2);

  // 10. out_proj + residual -> d_out  (32 m-tiles x 16 n-tiles, 64x128)
  gemm_bt64<true><<<32 * 16, 256, 0, stream>>>(y2, Wb_out, out, x,
                                               4096, 2048, 2048, 32, 16, 4);
}

// Round 4
// 482.722 us; speedup vs baseline: 1.1049x; 1.0050x over previous
//
#include <hip/hip_runtime.h>
#include <stdint.h>

// ---------------------------------------------------------------------------
// FalconMamba2 SSM decoder layer, MI355X (gfx950) — round 4
// Round-3 + register-tiled ssd_intra / ssd_off (4x16 output tiles per thread,
// prefetched coefficient streams). SSD was LDS-read-throughput bound.
// ---------------------------------------------------------------------------

typedef __bf16 bf16x8 __attribute__((ext_vector_type(8)));
typedef float  f32x4  __attribute__((ext_vector_type(4)));

#define DEVFN __device__ __forceinline__

DEVFN unsigned short f2b(float f) {
  uint32_t u = __builtin_bit_cast(uint32_t, f);
  u += 0x7fffu + ((u >> 16) & 1u);          // round-to-nearest-even
  return (unsigned short)(u >> 16);
}

// bijective XCD swizzle (m204) + GROUP-major supertiling
DEVFN void tile_map(int bid, int nwg, int nm, int nn, int grp, int& mt, int& nt) {
  const int q = nwg >> 3, r = nwg & 7;
  const int xcd = bid & 7, lid = bid >> 3;
  const int wg = (xcd < r ? xcd * (q + 1) : r * (q + 1) + (xcd - r) * q) + lid;
  const int per = grp * nn;
  const int g = wg / per;
  const int rem = wg - g * per;
  const int lim = nm - g * grp;
  const int gm = lim < grp ? lim : grp;
  mt = g * grp + rem % gm;
  nt = rem / gm;
}

// ---------------------------------------------------------------------------
// fp32 -> bf16 conversion with zero-padding tail (pad rows for GEMM tiles)
// ---------------------------------------------------------------------------
__global__ void f32_to_bf16_pad(const float* __restrict__ src,
                                unsigned short* __restrict__ dst,
                                long srcElems, long dstElems) {
  const long i = ((long)blockIdx.x * 256 + threadIdx.x) * 4;
  if (i >= dstElems) return;
  ushort4 o;
  if (i < srcElems) {
    float4 v = *reinterpret_cast<const float4*>(src + i);
    o.x = f2b(v.x); o.y = f2b(v.y); o.z = f2b(v.z); o.w = f2b(v.w);
  } else {
    o.x = 0; o.y = 0; o.z = 0; o.w = 0;
  }
  *reinterpret_cast<ushort4*>(dst + i) = o;
}

// ---------------------------------------------------------------------------
// input RMSNorm: x[2048][2048] f32 -> h bf16
// ---------------------------------------------------------------------------
__global__ __launch_bounds__(256) void rmsnorm_in(
    const float* __restrict__ x, const float* __restrict__ w,
    unsigned short* __restrict__ h) {
  const int row = blockIdx.x;
  const float* xr = x + (size_t)row * 2048;
  const int base = threadIdx.x * 8;
  float4 v0 = *reinterpret_cast<const float4*>(xr + base);
  float4 v1 = *reinterpret_cast<const float4*>(xr + base + 4);
  float ss = v0.x*v0.x + v0.y*v0.y + v0.z*v0.z + v0.w*v0.w
           + v1.x*v1.x + v1.y*v1.y + v1.z*v1.z + v1.w*v1.w;
  __shared__ float red[4];
#pragma unroll
  for (int off = 32; off > 0; off >>= 1) ss += __shfl_xor(ss, off);
  if ((threadIdx.x & 63) == 0) red[threadIdx.x >> 6] = ss;
  __syncthreads();
  ss = red[0] + red[1] + red[2] + red[3];
  const float scale = rsqrtf(ss * (1.0f / 2048.0f) + 1e-5f);
  float vals[8] = {v0.x, v0.y, v0.z, v0.w, v1.x, v1.y, v1.z, v1.w};
  unsigned short o[8];
#pragma unroll
  for (int j = 0; j < 8; ++j) o[j] = f2b(vals[j] * scale * w[base + j]);
  ushort4 a, b;
  a.x = o[0]; a.y = o[1]; a.z = o[2]; a.w = o[3];
  b.x = o[4]; b.y = o[5]; b.z = o[6]; b.w = o[7];
  *reinterpret_cast<ushort4*>(h + (size_t)row * 2048 + base)     = a;
  *reinterpret_cast<ushort4*>(h + (size_t)row * 2048 + base + 4) = b;
}

// ---------------------------------------------------------------------------
// bf16 GEMM, C[M,N] = A[M,K] @ B[N,K]^T, fp32 out. 128x128 tile, BK=64,
// 4 waves (2x2), each wave 64x64 via 4x4x2 mfma 16x16x32. 1D swizzled grid.
// ---------------------------------------------------------------------------
template<bool RES>
__global__ __launch_bounds__(256, 2) void gemm_bt(
    const unsigned short* __restrict__ A, const unsigned short* __restrict__ B,
    float* __restrict__ C, const float* __restrict__ res,
    int K, int Nc, int ldc, int nm, int nn, int grp) {
  __shared__ __align__(16) unsigned short As[128 * 64];
  __shared__ __align__(16) unsigned short Bs[128 * 64];
  int mt, nt;
  tile_map(blockIdx.x, nm * nn, nm, nn, grp, mt, nt);
  const int m0 = mt * 128;
  const int n0 = nt * 128;
  const int tid  = threadIdx.x;
  const int wid  = tid >> 6;
  const int lane = tid & 63;
  const int wm   = (wid >> 1) * 64;
  const int wn   = (wid & 1) * 64;
  const int lrow = lane & 15;
  const int lk   = (lane >> 4) * 8;

  f32x4 acc[4][4] = {};

  for (int k0 = 0; k0 < K; k0 += 64) {
#pragma unroll
    for (int i = 0; i < 4; ++i) {
      const int ci = tid + i * 256;             // [0, 1024)
      const int r = ci >> 3, cc = (ci & 7) * 8;
      __builtin_amdgcn_global_load_lds(
          (const __attribute__((address_space(1))) void*)(A + (size_t)(m0 + r) * K + k0 + cc),
          (__attribute__((address_space(3))) void*)(As + ci * 8), 16, 0, 0);
      __builtin_amdgcn_global_load_lds(
          (const __attribute__((address_space(1))) void*)(B + (size_t)(n0 + r) * K + k0 + cc),
          (__attribute__((address_space(3))) void*)(Bs + ci * 8), 16, 0, 0);
    }
    __syncthreads();   // compiler emits s_waitcnt vmcnt(0) before s_barrier

    bf16x8 af[4][2], bf[4][2];
#pragma unroll
    for (int m = 0; m < 4; ++m)
#pragma unroll
      for (int kk = 0; kk < 2; ++kk)
        af[m][kk] = *reinterpret_cast<const bf16x8*>(&As[(wm + m * 16 + lrow) * 64 + kk * 32 + lk]);
#pragma unroll
    for (int n = 0; n < 4; ++n)
#pragma unroll
      for (int kk = 0; kk < 2; ++kk)
        bf[n][kk] = *reinterpret_cast<const bf16x8*>(&Bs[(wn + n * 16 + lrow) * 64 + kk * 32 + lk]);
#pragma unroll
    for (int kk = 0; kk < 2; ++kk)
#pragma unroll
      for (int m = 0; m < 4; ++m)
#pragma unroll
        for (int n = 0; n < 4; ++n)
          acc[m][n] = __builtin_amdgcn_mfma_f32_16x16x32_bf16(af[m][kk], bf[n][kk], acc[m][n], 0, 0, 0);
    __syncthreads();
  }

  // C/D layout: col = lane&15, row = (lane>>4)*4 + reg  [m89/m91 verified]
#pragma unroll
  for (int m = 0; m < 4; ++m) {
#pragma unroll
    for (int n = 0; n < 4; ++n) {
      const int col = n0 + wn + n * 16 + lrow;
      if (col < Nc) {
#pragma unroll
        for (int v = 0; v < 4; ++v) {
          const int row = m0 + wm + m * 16 + (lane >> 4) * 4 + v;
          const size_t idx = (size_t)row * ldc + col;
          float val = acc[m][n][v];
          if (RES) val += res[idx];
          C[idx] = val;
        }
      }
    }
  }
}

// ---------------------------------------------------------------------------
// bf16 GEMM variant: 64x128 tile, BK=64, 4 waves (2x2), wave 32x64 (acc 2x4).
// ---------------------------------------------------------------------------
template<bool RES>
__global__ __launch_bounds__(256, 2) void gemm_bt64(
    const unsigned short* __restrict__ A, const unsigned short* __restrict__ B,
    float* __restrict__ C, const float* __restrict__ res,
    int K, int Nc, int ldc, int nm, int nn, int grp) {
  __shared__ __align__(16) unsigned short As[64 * 64];
  __shared__ __align__(16) unsigned short Bs[128 * 64];
  int mt, nt;
  tile_map(blockIdx.x, nm * nn, nm, nn, grp, mt, nt);
  const int m0 = mt * 64;
  const int n0 = nt * 128;
  const int tid  = threadIdx.x;
  const int wid  = tid >> 6;
  const int lane = tid & 63;
  const int wm   = (wid >> 1) * 32;
  const int wn   = (wid & 1) * 64;
  const int lrow = lane & 15;
  const int lk   = (lane >> 4) * 8;

  f32x4 acc[2][4] = {};

  for (int k0 = 0; k0 < K; k0 += 64) {
#pragma unroll
    for (int i = 0; i < 2; ++i) {          // A: 64x64 = 512 chunks
      const int ci = tid + i * 256;
      const int r = ci >> 3, cc = (ci & 7) * 8;
      __builtin_amdgcn_global_load_lds(
          (const __attribute__((address_space(1))) void*)(A + (size_t)(m0 + r) * K + k0 + cc),
          (__attribute__((address_space(3))) void*)(As + ci * 8), 16, 0, 0);
    }
#pragma unroll
    for (int i = 0; i < 4; ++i) {          // B: 128x64 = 1024 chunks
      const int ci = tid + i * 256;
      const int r = ci >> 3, cc = (ci & 7) * 8;
      __builtin_amdgcn_global_load_lds(
          (const __attribute__((address_space(1))) void*)(B + (size_t)(n0 + r) * K + k0 + cc),
          (__attribute__((address_space(3))) void*)(Bs + ci * 8), 16, 0, 0);
    }
    __syncthreads();

    bf16x8 af[2][2], bf[4][2];
#pragma unroll
    for (int m = 0; m < 2; ++m)
#pragma unroll
      for (int kk = 0; kk < 2; ++kk)
        af[m][kk] = *reinterpret_cast<const bf16x8*>(&As[(wm + m * 16 + lrow) * 64 + kk * 32 + lk]);
#pragma unroll
    for (int n = 0; n < 4; ++n)
#pragma unroll
      for (int kk = 0; kk < 2; ++kk)
        bf[n][kk] = *reinterpret_cast<const bf16x8*>(&Bs[(wn + n * 16 + lrow) * 64 + kk * 32 + lk]);
#pragma unroll
    for (int kk = 0; kk < 2; ++kk)
#pragma unroll
      for (int m = 0; m < 2; ++m)
#pragma unroll
        for (int n = 0; n < 4; ++n)
          acc[m][n] = __builtin_amdgcn_mfma_f32_16x16x32_bf16(af[m][kk], bf[n][kk], acc[m][n], 0, 0, 0);
    __syncthreads();
  }

#pragma unroll
  for (int m = 0; m < 2; ++m) {
#pragma unroll
    for (int n = 0; n < 4; ++n) {
      const int col = n0 + wn + n * 16 + lrow;
      if (col < Nc) {
#pragma unroll
        for (int v = 0; v < 4; ++v) {
          const int row = m0 + wm + m * 16 + (lane >> 4) * 4 + v;
          const size_t idx = (size_t)row * ldc + col;
          float val = acc[m][n][v];
          if (RES) val += res[idx];
          C[idx] = val;
        }
      }
    }
  }
}

// ---------------------------------------------------------------------------
// causal depthwise conv(K=4) + SiLU; softplus(dt+bias). 16 l per thread.
// proj row layout: [z 0..4095 | xBC 4096..8447 | dt 8448..8511]
// Also emits CT[c][n][l] (transposed C) for ssd_off.
// ---------------------------------------------------------------------------
__global__ __launch_bounds__(256) void conv_silu_dt(
    const float* __restrict__ proj, const float* __restrict__ conv_w,
    const float* __restrict__ conv_b, const float* __restrict__ dt_bias,
    float* __restrict__ xs, float* __restrict__ BC, float* __restrict__ CT,
    float* __restrict__ dtc) {
  const int cch = blockIdx.x * 256 + threadIdx.x;
  const int l0 = blockIdx.y * 16;
  if (cch < 4352) {
    const float4 w = *reinterpret_cast<const float4*>(conv_w + (size_t)cch * 4);
    const float b = conv_b[cch];
    const float* pcol = proj + 4096 + cch;
    float w0, w1, w2;
    w0 = (l0 >= 3) ? pcol[(size_t)(l0 - 3) * 8512] : 0.0f;
    w1 = (l0 >= 2) ? pcol[(size_t)(l0 - 2) * 8512] : 0.0f;
    w2 = (l0 >= 1) ? pcol[(size_t)(l0 - 1) * 8512] : 0.0f;
#pragma unroll
    for (int i = 0; i < 16; ++i) {
      const int l = l0 + i;
      const float cur = pcol[(size_t)l * 8512];
      float acc = b + w0 * w.x + w1 * w.y + w2 * w.z + cur * w.w;
      w0 = w1; w1 = w2; w2 = cur;
      acc = acc / (1.0f + __expf(-acc));   // silu
      if (cch < 4096) {
        xs[(size_t)l * 4096 + cch] = acc;
      } else {
        BC[(size_t)l * 256 + (cch - 4096)] = acc;
        if (cch >= 4224) {
          const int n = cch - 4224;
          const int c = l >> 8;
          CT[((size_t)(c * 128) + n) * 256 + (l & 255)] = acc;
        }
      }
    }
  } else if (cch < 4416) {
    const int hh = cch - 4352;
    const float bias = dt_bias[hh];
#pragma unroll
    for (int i = 0; i < 16; ++i) {
      const int l = l0 + i;
      const float v = proj[(size_t)l * 8512 + 8448 + hh] + bias;
      dtc[(size_t)l * 64 + hh] = (v > 20.0f) ? v : log1pf(expf(v));
    }
  }
}

// ---------------------------------------------------------------------------
// per-(chunk,head) inclusive cumsum of dA = dt*A over the 256-long chunk
// ---------------------------------------------------------------------------
__global__ __launch_bounds__(256) void scan_dA(
    const float* __restrict__ dtc, const float* __restrict__ A_log,
    float* __restrict__ dAc, float* __restrict__ cdec) {
  const int bx = blockIdx.x;              // c*64 + h
  const int c = bx >> 6, h = bx & 63;
  const int l = threadIdx.x;
  __shared__ float buf[256];
  const float Ah = -expf(A_log[h]);
  buf[l] = dtc[(size_t)(c * 256 + l) * 64 + h] * Ah;
  __syncthreads();
  for (int off = 1; off < 256; off <<= 1) {
    const float t = (l >= off) ? buf[l - off] : 0.0f;
    __syncthreads();
    buf[l] += t;
    __syncthreads();
  }
  dAc[(size_t)bx * 256 + l] = buf[l];
  if (l == 255) cdec[bx] = expf(buf[255]);
}

// ---------------------------------------------------------------------------
// CBT[c][s][l] = sum_n C[c,l,n] * B[c,s,n]  (transposed: Y_diag reads float4
// along l). One block per (c,l); thread = s.
// ---------------------------------------------------------------------------
__global__ __launch_bounds__(256) void cb_k(const float* __restrict__ BC,
                                            float* __restrict__ CBT) {
  const int gl = blockIdx.x;              // c*256 + l
  const int c = gl >> 8, l = gl & 255;
  const int s = threadIdx.x;
  __shared__ float Crow[128];
  if (threadIdx.x < 128) Crow[threadIdx.x] = BC[(size_t)gl * 256 + 128 + threadIdx.x];
  __syncthreads();
  const float* Br = BC + (size_t)(c * 256 + s) * 256;
  float acc = 0.0f;
#pragma unroll 4
  for (int n = 0; n < 128; ++n) acc += Crow[n] * Br[n];
  CBT[((size_t)(c * 256) + s) * 256 + l] = acc;
}

// ---------------------------------------------------------------------------
// intra-chunk: Y_diag + D*xs -> y (in-place over xs), and per-chunk states.
// one block per (chunk, head); xs tile [256][64] staged in LDS (64 KB).
// Register-tiled: thread = (lg,pg) computes 4 l-rows x 16 p-cols.
// ---------------------------------------------------------------------------
__global__ __launch_bounds__(256, 2) void ssd_intra(
    const float* xs, const float* __restrict__ BC,
    const float* __restrict__ dtc, const float* __restrict__ dAc,
    const float* __restrict__ CBT, const float* __restrict__ Dp,
    float* y, float* __restrict__ states) {
  const int bx = blockIdx.x;              // c*64 + h
  const int c = bx >> 6, h = bx & 63;
  __shared__ __align__(16) float xsL[256 * 64];
  __shared__ float dAL[256];
  __shared__ float dtL[256];
  __shared__ float wL[256];
  const int tid = threadIdx.x;
#pragma unroll 8
  for (int i = 0; i < 64; ++i) {
    const int idx = tid + i * 256;        // idx = s*64 + p
    xsL[idx] = xs[(size_t)(c * 256 + (idx >> 6)) * 4096 + h * 64 + (idx & 63)];
  }
  dAL[tid] = dAc[(size_t)bx * 256 + tid];
  dtL[tid] = dtc[(size_t)(c * 256 + tid) * 64 + h];
  __syncthreads();
  const float dAlast = dAL[255];
  wL[tid] = __expf(dAlast - dAL[tid]) * dtL[tid];
  __syncthreads();

  const int pg = tid & 3;                 // 16-col group
  const int lg = tid >> 2;                // 4-row group
  const int l0 = lg * 4;

  // ---- Y_diag: acc[4 rows][16 cols]; coef stream CBT prefetched 1 deep.
  float dAl[4];
#pragma unroll
  for (int i = 0; i < 4; ++i) dAl[i] = dAL[l0 + i];
  const float* CBbase = CBT + (size_t)c * 65536 + l0;   // + s*256
  f32x4 acc[4][4] = {};
  const int smax = l0 + 3;
  float4 cb = *reinterpret_cast<const float4*>(CBbase);
  for (int s = 0; s <= smax; ++s) {
    const int sn = (s < smax) ? s + 1 : smax;
    float4 cbn = *reinterpret_cast<const float4*>(CBbase + (size_t)sn * 256);
    const float dAs = dAL[s];
    const float dts = dtL[s];
    float m[4];
#pragma unroll
    for (int i = 0; i < 4; ++i) {
      const float e = __expf(dAl[i] - dAs) * dts * (&cb.x)[i];
      m[i] = (s <= l0 + i) ? e : 0.0f;    // select (not mul) discards inf/NaN
    }
    const f32x4* xr = reinterpret_cast<const f32x4*>(&xsL[s * 64 + pg * 16]);
#pragma unroll
    for (int i = 0; i < 4; ++i)
#pragma unroll
      for (int q = 0; q < 4; ++q) acc[i][q] += m[i] * xr[q];
    cb = cbn;
  }
  const float Dh = Dp[h];
#pragma unroll
  for (int i = 0; i < 4; ++i) {
    float* yo = y + (size_t)(c * 256 + l0 + i) * 4096 + h * 64 + pg * 16;
    const f32x4* xl = reinterpret_cast<const f32x4*>(&xsL[(l0 + i) * 64 + pg * 16]);
#pragma unroll
    for (int q = 0; q < 4; ++q) {
      f32x4 o = acc[i][q] + Dh * xl[q];
      *reinterpret_cast<f32x4*>(yo + q * 4) = o;
    }
  }

  // ---- states[c][h][n][p] = sum_s B[s,n]*w[s]*xs[s,p]
  // thread = (ng,pg): 2 n-rows x 16 p-cols; B stream prefetched 1 deep.
  const int n0 = (tid >> 2) * 2;
  const float* Bbase = BC + (size_t)(c * 256) * 256 + n0;  // + s*256
  f32x4 st[2][4] = {};
  float2 bv = *reinterpret_cast<const float2*>(Bbase);
  for (int s = 0; s < 256; ++s) {
    const int sn = (s < 255) ? s + 1 : 255;
    float2 bvn = *reinterpret_cast<const float2*>(Bbase + (size_t)sn * 256);
    const float w = wL[s];
    const float b0 = bv.x * w, b1 = bv.y * w;
    const f32x4* xr = reinterpret_cast<const f32x4*>(&xsL[s * 64 + pg * 16]);
#pragma unroll
    for (int q = 0; q < 4; ++q) { st[0][q] += b0 * xr[q]; st[1][q] += b1 * xr[q]; }
    bv = bvn;
  }
#pragma unroll
  for (int i = 0; i < 2; ++i) {
    float* so = states + ((size_t)bx * 128 + n0 + i) * 64 + pg * 16;
#pragma unroll
    for (int q = 0; q < 4; ++q) *reinterpret_cast<f32x4*>(so + q * 4) = st[i][q];
  }
}

// ---------------------------------------------------------------------------
// inter-chunk scan (8 sequential chunks), in-place: states[c] := prev_state[c]
// ---------------------------------------------------------------------------
__global__ void ssd_scan(float* __restrict__ states, const float* __restrict__ cdec) {
  const int i = blockIdx.x * 256 + threadIdx.x;   // < 64*8192
  const int h = i >> 13;
  const int r = i & 8191;
  float carry = 0.0f;
#pragma unroll
  for (int c = 0; c < 8; ++c) {
    const size_t idx = ((size_t)(c * 64 + h)) * 8192 + r;
    const float st = states[idx];
    states[idx] = carry;                           // emit state BEFORE chunk
    carry = carry * cdec[c * 64 + h] + st;
  }
}

// ---------------------------------------------------------------------------
// Y_off: y[l,h,p] += exp(dAc[l]) * sum_n C[l,n] * prev[h][n][p]
// Register-tiled 4l x 16p; CT stream prefetched 1 deep.
// ---------------------------------------------------------------------------
__global__ __launch_bounds__(256, 2) void ssd_off(
    const float* __restrict__ CT, const float* __restrict__ dAc,
    const float* __restrict__ prev, float* __restrict__ y) {
  const int bx = blockIdx.x;              // c*64 + h
  const int c = bx >> 6, h = bx & 63;
  __shared__ __align__(16) float pL[128 * 64];
  const int tid = threadIdx.x;
#pragma unroll 8
  for (int i = 0; i < 32; ++i) pL[tid + i * 256] = prev[(size_t)bx * 8192 + tid + i * 256];
  __syncthreads();
  const int pg = tid & 3;
  const int lg = tid >> 2;
  const int l0 = lg * 4;
  const float* Cbase = CT + (size_t)(c * 128) * 256 + l0;   // + n*256
  f32x4 acc[4][4] = {};
  float4 cv = *reinterpret_cast<const float4*>(Cbase);
  for (int n = 0; n < 128; ++n) {
    const int nn2 = (n < 127) ? n + 1 : 127;
    float4 cvn = *reinterpret_cast<const float4*>(Cbase + (size_t)nn2 * 256);
    const f32x4* xr = reinterpret_cast<const f32x4*>(&pL[n * 64 + pg * 16]);
#pragma unroll
    for (int i = 0; i < 4; ++i) {
      const float ci = (&cv.x)[i];
#pragma unroll
      for (int q = 0; q < 4; ++q) acc[i][q] += ci * xr[q];
    }
    cv = cvn;
  }
#pragma unroll
  for (int i = 0; i < 4; ++i) {
    const float eA = __expf(dAc[(size_t)bx * 256 + l0 + i]);
    float* yo = y + (size_t)(c * 256 + l0 + i) * 4096 + h * 64 + pg * 16;
#pragma unroll
    for (int q = 0; q < 4; ++q) {
      f32x4 cur = *reinterpret_cast<const f32x4*>(yo + q * 4);
      cur += eA * acc[i][q];
      *reinterpret_cast<f32x4*>(yo + q * 4) = cur;
    }
  }
}

// ---------------------------------------------------------------------------
// gated RMSNorm: y2 = rmsnorm(y * silu(z)) * norm_w  -> bf16
// ---------------------------------------------------------------------------
__global__ __launch_bounds__(256) void gated_rmsnorm(
    const float* __restrict__ y, const float* __restrict__ proj,
    const float* __restrict__ nw, unsigned short* __restrict__ y2) {
  const int row = blockIdx.x;
  const float* yr = y + (size_t)row * 4096;
  const float* zr = proj + (size_t)row * 8512;    // z = cols 0..4095
  const int base = threadIdx.x * 16;
  float g[16];
  float ss = 0.0f;
#pragma unroll
  for (int j = 0; j < 16; j += 4) {
    const float4 yv = *reinterpret_cast<const float4*>(yr + base + j);
    const float4 zv = *reinterpret_cast<const float4*>(zr + base + j);
    const float a0 = yv.x * (zv.x / (1.0f + expf(-zv.x)));
    const float a1 = yv.y * (zv.y / (1.0f + expf(-zv.y)));
    const float a2 = yv.z * (zv.z / (1.0f + expf(-zv.z)));
    const float a3 = yv.w * (zv.w / (1.0f + expf(-zv.w)));
    g[j] = a0; g[j+1] = a1; g[j+2] = a2; g[j+3] = a3;
    ss += a0*a0 + a1*a1 + a2*a2 + a3*a3;
  }
  __shared__ float red[4];
#pragma unroll
  for (int off = 32; off > 0; off >>= 1) ss += __shfl_xor(ss, off);
  if ((threadIdx.x & 63) == 0) red[threadIdx.x >> 6] = ss;
  __syncthreads();
  ss = red[0] + red[1] + red[2] + red[3];
  const float scale = rsqrtf(ss * (1.0f / 4096.0f) + 1e-5f);
#pragma unroll
  for (int j = 0; j < 16; j += 4) {
    ushort4 o;
    o.x = f2b(g[j]   * scale * nw[base + j]);
    o.y = f2b(g[j+1] * scale * nw[base + j + 1]);
    o.z = f2b(g[j+2] * scale * nw[base + j + 2]);
    o.w = f2b(g[j+3] * scale * nw[base + j + 3]);
    *reinterpret_cast<ushort4*>(y2 + (size_t)row * 4096 + base + j) = o;
  }
}

// ---------------------------------------------------------------------------
extern "C" void kernel_launch(void* const* d_in, const int* in_sizes, int n_in,
                              void* d_out, int out_size, void* d_ws, size_t ws_size,
                              hipStream_t stream) {
  const float* x       = (const float*)d_in[0];
  const float* rms_w   = (const float*)d_in[1];
  const float* W_in    = (const float*)d_in[2];
  const float* conv_w  = (const float*)d_in[3];
  const float* conv_b  = (const float*)d_in[4];
  const float* dt_bias = (const float*)d_in[5];
  const float* A_log   = (const float*)d_in[6];
  const float* Dp      = (const float*)d_in[7];
  const float* norm_w  = (const float*)d_in[8];
  const float* W_out   = (const float*)d_in[9];
  float* out = (float*)d_out;

  char* ws = (char*)d_ws;
  size_t off = 0;
  auto alloc = [&](size_t bytes) {
    void* p = ws + off;
    off += (bytes + 255) & ~(size_t)255;
    return p;
  };
  unsigned short* Wb_in  = (unsigned short*)alloc((size_t)8576 * 2048 * 2); // padded rows
  unsigned short* Wb_out = (unsigned short*)alloc((size_t)2048 * 4096 * 2);
  unsigned short* hbuf   = (unsigned short*)alloc((size_t)2048 * 2048 * 2);
  float* proj   = (float*)alloc((size_t)2048 * 8512 * 4);
  float* xsbuf  = (float*)alloc((size_t)2048 * 4096 * 4);   // xs, then y (in-place)
  float* BCbuf  = (float*)alloc((size_t)2048 * 256 * 4);
  float* CTbuf  = (float*)alloc((size_t)8 * 128 * 256 * 4);
  float* dtcbuf = (float*)alloc((size_t)2048 * 64 * 4);
  float* dAcbuf = (float*)alloc((size_t)512 * 256 * 4);
  float* cdec   = (float*)alloc((size_t)512 * 4);
  float* CBTbuf = (float*)alloc((size_t)8 * 256 * 256 * 4);
  float* states = (float*)alloc((size_t)512 * 128 * 64 * 4);
  unsigned short* y2 = Wb_in;   // reuse: Wb_in dead after in_proj GEMM

  (void)in_sizes; (void)n_in; (void)out_size; (void)ws_size;

  // weight conversion (every call; no caching allowed)
  f32_to_bf16_pad<<<(8576 * 2048 / 4 + 255) / 256, 256, 0, stream>>>(
      W_in, Wb_in, (long)8512 * 2048, (long)8576 * 2048);
  f32_to_bf16_pad<<<(2048 * 4096 / 4 + 255) / 256, 256, 0, stream>>>(
      W_out, Wb_out, (long)2048 * 4096, (long)2048 * 4096);

  // 1. input RMSNorm -> bf16
  rmsnorm_in<<<2048, 256, 0, stream>>>(x, rms_w, hbuf);

  // 2. in_proj: proj[2048,8512] = h @ W_in^T  (16 m-tiles x 67 n-tiles)
  gemm_bt<false><<<16 * 67, 256, 0, stream>>>(hbuf, Wb_in, proj, nullptr,
                                              2048, 8512, 8512, 16, 67, 4);

  // 3. conv + SiLU + softplus(dt); emits BC and transposed CT
  conv_silu_dt<<<dim3(18, 128), 256, 0, stream>>>(proj, conv_w, conv_b, dt_bias,
                                                  xsbuf, BCbuf, CTbuf, dtcbuf);

  // 4. per-(chunk,head) cumsum of dt*A; chunk decay
  scan_dA<<<512, 256, 0, stream>>>(dtcbuf, A_log, dAcbuf, cdec);

  // 5. CBT = (C @ B^T)^T per chunk
  cb_k<<<2048, 256, 0, stream>>>(BCbuf, CBTbuf);

  // 6. intra-chunk Y_diag + D*xs (y in-place over xs) and chunk states
  ssd_intra<<<512, 256, 0, stream>>>(xsbuf, BCbuf, dtcbuf, dAcbuf, CBTbuf, Dp,
                                     xsbuf, states);

  // 7. inter-chunk recurrence (in-place: states -> prev_states)
  ssd_scan<<<2048, 256, 0, stream>>>(states, cdec);

  // 8. Y_off accumulate into y
  ssd_off<<<512, 256, 0, stream>>>(CTbuf, dAcbuf, states, xsbuf);

  // 9. gated RMSNorm -> bf16
  gated_rmsnorm<<<2048, 256, 0, stream>>>(xsbuf, proj, norm_w, y2);

  // 10. out_proj + residual -> d_out  (32 m-tiles x 16 n-tiles, 64x128)
  gemm_bt64<true><<<32 * 16, 256, 0, stream>>>(y2, Wb_out, out, x,
                                               4096, 2048, 2048, 32, 16, 4);
}

// Round 5
// 372.678 us; speedup vs baseline: 1.4312x; 1.2953x over previous
//
#include <hip/hip_runtime.h>
#include <stdint.h>

// ---------------------------------------------------------------------------
// FalconMamba2 SSM decoder layer, MI355X (gfx950) — round 5
// SSD matmuls (Y_diag, states, Y_off) moved to bf16 MFMA. fp32 SSD was
// VALU-floored at ~80+ us; MFMA compresses it ~10x.
// ---------------------------------------------------------------------------

typedef __bf16 bf16x8 __attribute__((ext_vector_type(8)));
typedef float  f32x4  __attribute__((ext_vector_type(4)));

#define DEVFN __device__ __forceinline__

DEVFN unsigned short f2b(float f) {
  uint32_t u = __builtin_bit_cast(uint32_t, f);
  u += 0x7fffu + ((u >> 16) & 1u);          // round-to-nearest-even
  return (unsigned short)(u >> 16);
}
DEVFN float b2f(unsigned short u) {
  uint32_t x = (uint32_t)u << 16;
  return __builtin_bit_cast(float, x);
}
DEVFN bf16x8 pack8(const float (&m)[8]) {
  bf16x8 r;
#pragma unroll
  for (int t = 0; t < 8; ++t) r[t] = (__bf16)m[t];
  return r;
}

// bijective XCD swizzle (m204) + GROUP-major supertiling
DEVFN void tile_map(int bid, int nwg, int nm, int nn, int grp, int& mt, int& nt) {
  const int q = nwg >> 3, r = nwg & 7;
  const int xcd = bid & 7, lid = bid >> 3;
  const int wg = (xcd < r ? xcd * (q + 1) : r * (q + 1) + (xcd - r) * q) + lid;
  const int per = grp * nn;
  const int g = wg / per;
  const int rem = wg - g * per;
  const int lim = nm - g * grp;
  const int gm = lim < grp ? lim : grp;
  mt = g * grp + rem % gm;
  nt = rem / gm;
}

// ---------------------------------------------------------------------------
__global__ void f32_to_bf16_pad(const float* __restrict__ src,
                                unsigned short* __restrict__ dst,
                                long srcElems, long dstElems) {
  const long i = ((long)blockIdx.x * 256 + threadIdx.x) * 4;
  if (i >= dstElems) return;
  ushort4 o;
  if (i < srcElems) {
    float4 v = *reinterpret_cast<const float4*>(src + i);
    o.x = f2b(v.x); o.y = f2b(v.y); o.z = f2b(v.z); o.w = f2b(v.w);
  } else {
    o.x = 0; o.y = 0; o.z = 0; o.w = 0;
  }
  *reinterpret_cast<ushort4*>(dst + i) = o;
}

// ---------------------------------------------------------------------------
__global__ __launch_bounds__(256) void rmsnorm_in(
    const float* __restrict__ x, const float* __restrict__ w,
    unsigned short* __restrict__ h) {
  const int row = blockIdx.x;
  const float* xr = x + (size_t)row * 2048;
  const int base = threadIdx.x * 8;
  float4 v0 = *reinterpret_cast<const float4*>(xr + base);
  float4 v1 = *reinterpret_cast<const float4*>(xr + base + 4);
  float ss = v0.x*v0.x + v0.y*v0.y + v0.z*v0.z + v0.w*v0.w
           + v1.x*v1.x + v1.y*v1.y + v1.z*v1.z + v1.w*v1.w;
  __shared__ float red[4];
#pragma unroll
  for (int off = 32; off > 0; off >>= 1) ss += __shfl_xor(ss, off);
  if ((threadIdx.x & 63) == 0) red[threadIdx.x >> 6] = ss;
  __syncthreads();
  ss = red[0] + red[1] + red[2] + red[3];
  const float scale = rsqrtf(ss * (1.0f / 2048.0f) + 1e-5f);
  float vals[8] = {v0.x, v0.y, v0.z, v0.w, v1.x, v1.y, v1.z, v1.w};
  unsigned short o[8];
#pragma unroll
  for (int j = 0; j < 8; ++j) o[j] = f2b(vals[j] * scale * w[base + j]);
  ushort4 a, b;
  a.x = o[0]; a.y = o[1]; a.z = o[2]; a.w = o[3];
  b.x = o[4]; b.y = o[5]; b.z = o[6]; b.w = o[7];
  *reinterpret_cast<ushort4*>(h + (size_t)row * 2048 + base)     = a;
  *reinterpret_cast<ushort4*>(h + (size_t)row * 2048 + base + 4) = b;
}

// ---------------------------------------------------------------------------
// bf16 GEMM, C[M,N] = A[M,K] @ B[N,K]^T. 128x128 tile, BK=64 (unchanged).
// ---------------------------------------------------------------------------
template<bool RES>
__global__ __launch_bounds__(256, 2) void gemm_bt(
    const unsigned short* __restrict__ A, const unsigned short* __restrict__ B,
    float* __restrict__ C, const float* __restrict__ res,
    int K, int Nc, int ldc, int nm, int nn, int grp) {
  __shared__ __align__(16) unsigned short As[128 * 64];
  __shared__ __align__(16) unsigned short Bs[128 * 64];
  int mt, nt;
  tile_map(blockIdx.x, nm * nn, nm, nn, grp, mt, nt);
  const int m0 = mt * 128;
  const int n0 = nt * 128;
  const int tid  = threadIdx.x;
  const int wid  = tid >> 6;
  const int lane = tid & 63;
  const int wm   = (wid >> 1) * 64;
  const int wn   = (wid & 1) * 64;
  const int lrow = lane & 15;
  const int lk   = (lane >> 4) * 8;

  f32x4 acc[4][4] = {};

  for (int k0 = 0; k0 < K; k0 += 64) {
#pragma unroll
    for (int i = 0; i < 4; ++i) {
      const int ci = tid + i * 256;
      const int r = ci >> 3, cc = (ci & 7) * 8;
      __builtin_amdgcn_global_load_lds(
          (const __attribute__((address_space(1))) void*)(A + (size_t)(m0 + r) * K + k0 + cc),
          (__attribute__((address_space(3))) void*)(As + ci * 8), 16, 0, 0);
      __builtin_amdgcn_global_load_lds(
          (const __attribute__((address_space(1))) void*)(B + (size_t)(n0 + r) * K + k0 + cc),
          (__attribute__((address_space(3))) void*)(Bs + ci * 8), 16, 0, 0);
    }
    __syncthreads();

    bf16x8 af[4][2], bf[4][2];
#pragma unroll
    for (int m = 0; m < 4; ++m)
#pragma unroll
      for (int kk = 0; kk < 2; ++kk)
        af[m][kk] = *reinterpret_cast<const bf16x8*>(&As[(wm + m * 16 + lrow) * 64 + kk * 32 + lk]);
#pragma unroll
    for (int n = 0; n < 4; ++n)
#pragma unroll
      for (int kk = 0; kk < 2; ++kk)
        bf[n][kk] = *reinterpret_cast<const bf16x8*>(&Bs[(wn + n * 16 + lrow) * 64 + kk * 32 + lk]);
#pragma unroll
    for (int kk = 0; kk < 2; ++kk)
#pragma unroll
      for (int m = 0; m < 4; ++m)
#pragma unroll
        for (int n = 0; n < 4; ++n)
          acc[m][n] = __builtin_amdgcn_mfma_f32_16x16x32_bf16(af[m][kk], bf[n][kk], acc[m][n], 0, 0, 0);
    __syncthreads();
  }

#pragma unroll
  for (int m = 0; m < 4; ++m) {
#pragma unroll
    for (int n = 0; n < 4; ++n) {
      const int col = n0 + wn + n * 16 + lrow;
      if (col < Nc) {
#pragma unroll
        for (int v = 0; v < 4; ++v) {
          const int row = m0 + wm + m * 16 + (lane >> 4) * 4 + v;
          const size_t idx = (size_t)row * ldc + col;
          float val = acc[m][n][v];
          if (RES) val += res[idx];
          C[idx] = val;
        }
      }
    }
  }
}

// ---------------------------------------------------------------------------
// bf16 GEMM variant: 64x128 tile (unchanged).
// ---------------------------------------------------------------------------
template<bool RES>
__global__ __launch_bounds__(256, 2) void gemm_bt64(
    const unsigned short* __restrict__ A, const unsigned short* __restrict__ B,
    float* __restrict__ C, const float* __restrict__ res,
    int K, int Nc, int ldc, int nm, int nn, int grp) {
  __shared__ __align__(16) unsigned short As[64 * 64];
  __shared__ __align__(16) unsigned short Bs[128 * 64];
  int mt, nt;
  tile_map(blockIdx.x, nm * nn, nm, nn, grp, mt, nt);
  const int m0 = mt * 64;
  const int n0 = nt * 128;
  const int tid  = threadIdx.x;
  const int wid  = tid >> 6;
  const int lane = tid & 63;
  const int wm   = (wid >> 1) * 32;
  const int wn   = (wid & 1) * 64;
  const int lrow = lane & 15;
  const int lk   = (lane >> 4) * 8;

  f32x4 acc[2][4] = {};

  for (int k0 = 0; k0 < K; k0 += 64) {
#pragma unroll
    for (int i = 0; i < 2; ++i) {
      const int ci = tid + i * 256;
      const int r = ci >> 3, cc = (ci & 7) * 8;
      __builtin_amdgcn_global_load_lds(
          (const __attribute__((address_space(1))) void*)(A + (size_t)(m0 + r) * K + k0 + cc),
          (__attribute__((address_space(3))) void*)(As + ci * 8), 16, 0, 0);
    }
#pragma unroll
    for (int i = 0; i < 4; ++i) {
      const int ci = tid + i * 256;
      const int r = ci >> 3, cc = (ci & 7) * 8;
      __builtin_amdgcn_global_load_lds(
          (const __attribute__((address_space(1))) void*)(B + (size_t)(n0 + r) * K + k0 + cc),
          (__attribute__((address_space(3))) void*)(Bs + ci * 8), 16, 0, 0);
    }
    __syncthreads();

    bf16x8 af[2][2], bf[4][2];
#pragma unroll
    for (int m = 0; m < 2; ++m)
#pragma unroll
      for (int kk = 0; kk < 2; ++kk)
        af[m][kk] = *reinterpret_cast<const bf16x8*>(&As[(wm + m * 16 + lrow) * 64 + kk * 32 + lk]);
#pragma unroll
    for (int n = 0; n < 4; ++n)
#pragma unroll
      for (int kk = 0; kk < 2; ++kk)
        bf[n][kk] = *reinterpret_cast<const bf16x8*>(&Bs[(wn + n * 16 + lrow) * 64 + kk * 32 + lk]);
#pragma unroll
    for (int kk = 0; kk < 2; ++kk)
#pragma unroll
      for (int m = 0; m < 2; ++m)
#pragma unroll
        for (int n = 0; n < 4; ++n)
          acc[m][n] = __builtin_amdgcn_mfma_f32_16x16x32_bf16(af[m][kk], bf[n][kk], acc[m][n], 0, 0, 0);
    __syncthreads();
  }

#pragma unroll
  for (int m = 0; m < 2; ++m) {
#pragma unroll
    for (int n = 0; n < 4; ++n) {
      const int col = n0 + wn + n * 16 + lrow;
      if (col < Nc) {
#pragma unroll
        for (int v = 0; v < 4; ++v) {
          const int row = m0 + wm + m * 16 + (lane >> 4) * 4 + v;
          const size_t idx = (size_t)row * ldc + col;
          float val = acc[m][n][v];
          if (RES) val += res[idx];
          C[idx] = val;
        }
      }
    }
  }
}

// ---------------------------------------------------------------------------
// causal depthwise conv(K=4) + SiLU; softplus(dt+bias). 16 l per thread.
// Emits BC fp32 and BTb bf16 ([c][n][s], B transposed) for MFMA states.
// ---------------------------------------------------------------------------
__global__ __launch_bounds__(256) void conv_silu_dt(
    const float* __restrict__ proj, const float* __restrict__ conv_w,
    const float* __restrict__ conv_b, const float* __restrict__ dt_bias,
    float* __restrict__ xs, float* __restrict__ BC,
    unsigned short* __restrict__ BTb, float* __restrict__ dtc) {
  const int cch = blockIdx.x * 256 + threadIdx.x;
  const int l0 = blockIdx.y * 16;
  if (cch < 4352) {
    const float4 w = *reinterpret_cast<const float4*>(conv_w + (size_t)cch * 4);
    const float b = conv_b[cch];
    const float* pcol = proj + 4096 + cch;
    float w0, w1, w2;
    w0 = (l0 >= 3) ? pcol[(size_t)(l0 - 3) * 8512] : 0.0f;
    w1 = (l0 >= 2) ? pcol[(size_t)(l0 - 2) * 8512] : 0.0f;
    w2 = (l0 >= 1) ? pcol[(size_t)(l0 - 1) * 8512] : 0.0f;
#pragma unroll
    for (int i = 0; i < 16; ++i) {
      const int l = l0 + i;
      const float cur = pcol[(size_t)l * 8512];
      float acc = b + w0 * w.x + w1 * w.y + w2 * w.z + cur * w.w;
      w0 = w1; w1 = w2; w2 = cur;
      acc = acc / (1.0f + __expf(-acc));   // silu
      if (cch < 4096) {
        xs[(size_t)l * 4096 + cch] = acc;
      } else {
        BC[(size_t)l * 256 + (cch - 4096)] = acc;
        if (cch < 4224) {                   // B channels -> transposed bf16
          const int n = cch - 4096;
          BTb[((size_t)((l >> 8) * 128) + n) * 256 + (l & 255)] = f2b(acc);
        }
      }
    }
  } else if (cch < 4416) {
    const int hh = cch - 4352;
    const float bias = dt_bias[hh];
#pragma unroll
    for (int i = 0; i < 16; ++i) {
      const int l = l0 + i;
      const float v = proj[(size_t)l * 8512 + 8448 + hh] + bias;
      dtc[(size_t)l * 64 + hh] = (v > 20.0f) ? v : log1pf(expf(v));
    }
  }
}

// ---------------------------------------------------------------------------
__global__ __launch_bounds__(256) void scan_dA(
    const float* __restrict__ dtc, const float* __restrict__ A_log,
    float* __restrict__ dAc, float* __restrict__ cdec) {
  const int bx = blockIdx.x;              // c*64 + h
  const int c = bx >> 6, h = bx & 63;
  const int l = threadIdx.x;
  __shared__ float buf[256];
  const float Ah = -expf(A_log[h]);
  buf[l] = dtc[(size_t)(c * 256 + l) * 64 + h] * Ah;
  __syncthreads();
  for (int off = 1; off < 256; off <<= 1) {
    const float t = (l >= off) ? buf[l - off] : 0.0f;
    __syncthreads();
    buf[l] += t;
    __syncthreads();
  }
  dAc[(size_t)bx * 256 + l] = buf[l];
  if (l == 255) cdec[bx] = expf(buf[255]);
}

// ---------------------------------------------------------------------------
// CB[c][l][s] = sum_n C[c,l,n] * B[c,s,n]   (row-major, G=1 head-shared)
// ---------------------------------------------------------------------------
__global__ __launch_bounds__(256) void cb_k(const float* __restrict__ BC,
                                            float* __restrict__ CB) {
  const int gl = blockIdx.x;              // c*256 + l
  const int c = gl >> 8;
  const int s = threadIdx.x;
  __shared__ float Crow[128];
  if (threadIdx.x < 128) Crow[threadIdx.x] = BC[(size_t)gl * 256 + 128 + threadIdx.x];
  __syncthreads();
  const float* Br = BC + (size_t)(c * 256 + s) * 256;
  float acc = 0.0f;
#pragma unroll 4
  for (int n = 0; n < 128; ++n) acc += Crow[n] * Br[n];
  CB[(size_t)gl * 256 + s] = acc;
}

// ---------------------------------------------------------------------------
// MFMA states: statesT[c][h][p][n] = sum_s (w*xs)[s,p] * B[s,n]
// block = (c,h), 512 thr, 8 waves; A = w-folded xs^T (LDS bf16), B = BTb
// read direct from global bf16.
// ---------------------------------------------------------------------------
__global__ __launch_bounds__(512) void ssd_states(
    const float* __restrict__ xs, const unsigned short* __restrict__ BTb,
    const float* __restrict__ dtc, const float* __restrict__ dAc,
    float* __restrict__ statesT) {
  const int bx = blockIdx.x;              // c*64 + h
  const int c = bx >> 6, h = bx & 63;
  __shared__ __align__(16) unsigned short xwT[64 * 264];   // [p][s], +8 pad
  __shared__ float dAL[256], wLs[256];
  const int tid = threadIdx.x;
  const int lane = tid & 63;
  const int w = tid >> 6;

  if (tid < 256) dAL[tid] = dAc[(size_t)bx * 256 + tid];
  else           wLs[tid - 256] = dtc[(size_t)(c * 256 + (tid - 256)) * 64 + h];
  __syncthreads();
  if (tid < 256) wLs[tid] = __expf(dAL[255] - dAL[tid]) * wLs[tid];
  __syncthreads();
#pragma unroll
  for (int it = 0; it < 4; ++it) {
    const int gid = it * 512 + tid;
    const int p = gid & 63;
    const int s0 = (gid >> 6) * 8;
    bf16x8 r;
#pragma unroll
    for (int k = 0; k < 8; ++k)
      r[k] = (__bf16)(xs[(size_t)(c * 256 + s0 + k) * 4096 + h * 64 + p] * wLs[s0 + k]);
    *reinterpret_cast<bf16x8*>(&xwT[p * 264 + s0]) = r;
  }
  __syncthreads();

  const int pb = (w & 3) * 16;
  const int nb = (w >> 2) * 64;
  const int kcol = (lane >> 4) * 8;
  f32x4 acc[4] = {};
  for (int k = 0; k < 8; ++k) {
    bf16x8 av = *reinterpret_cast<const bf16x8*>(&xwT[(pb + (lane & 15)) * 264 + k * 32 + kcol]);
#pragma unroll
    for (int nf = 0; nf < 4; ++nf) {
      bf16x8 bv = *reinterpret_cast<const bf16x8*>(
          BTb + ((size_t)(c * 128) + nb + nf * 16 + (lane & 15)) * 256 + k * 32 + kcol);
      acc[nf] = __builtin_amdgcn_mfma_f32_16x16x32_bf16(av, bv, acc[nf], 0, 0, 0);
    }
  }
  const int rb = (lane >> 4) * 4;
#pragma unroll
  for (int nf = 0; nf < 4; ++nf) {
    const int n = nb + nf * 16 + (lane & 15);
#pragma unroll
    for (int v = 0; v < 4; ++v) {
      const int p = pb + rb + v;
      statesT[(size_t)bx * 8192 + p * 128 + n] = acc[nf][v];
    }
  }
}

// ---------------------------------------------------------------------------
// inter-chunk scan: emits prev-state (BEFORE chunk) as bf16 [c][h][p][n]
// ---------------------------------------------------------------------------
__global__ void ssd_scan(const float* __restrict__ statesT,
                         unsigned short* __restrict__ prevb,
                         const float* __restrict__ cdec) {
  const int i = blockIdx.x * 256 + threadIdx.x;   // < 64*8192
  const int h = i >> 13;
  const int r = i & 8191;
  float carry = 0.0f;
#pragma unroll
  for (int c = 0; c < 8; ++c) {
    const size_t idx = ((size_t)(c * 64 + h)) * 8192 + r;
    const float st = statesT[idx];
    prevb[idx] = f2b(carry);
    carry = carry * cdec[c * 64 + h] + st;
  }
}

// ---------------------------------------------------------------------------
// MFMA Y_diag + Y_off + D*xs -> y. block = (c,h), 512 thr, 8 waves.
// Wave w owns l-rows [32w,32w+32). M built in-register per k-iter:
//  off-diag j-blocks: exact rank-1 split exp(dAl-dAs)=u_l*v_s (anchor block
//  end => both <=1, no overflow); diagonal block: direct exp + tri-select.
// Y_off folded into same acc (A = C*exp(dAl), B = prev bf16 from global).
// ---------------------------------------------------------------------------
__global__ __launch_bounds__(512) void ssd_diag_off(
    const float* xs, const float* __restrict__ BC,
    const float* __restrict__ dtc, const float* __restrict__ dAc,
    const float* __restrict__ CB, const unsigned short* __restrict__ prevb,
    const float* __restrict__ Dp, float* y) {
  const int bx = blockIdx.x;              // c*64 + h
  const int c = bx >> 6, h = bx & 63;
  __shared__ __align__(16) unsigned short xsT[64 * 264];   // [p][s], +8 pad
  __shared__ float dAL[256], dtL[256], vdt[256];
  const int tid = threadIdx.x;
  const int lane = tid & 63;
  const int w = tid >> 6;

  if (tid < 256) {
    dAL[tid] = dAc[(size_t)bx * 256 + tid];
    dtL[tid] = dtc[(size_t)(c * 256 + tid) * 64 + h];
  }
  __syncthreads();
  if (tid < 256) vdt[tid] = __expf(dAL[tid | 31] - dAL[tid]) * dtL[tid];
#pragma unroll
  for (int it = 0; it < 4; ++it) {
    const int gid = it * 512 + tid;
    const int p = gid & 63;
    const int s0 = (gid >> 6) * 8;
    bf16x8 r;
#pragma unroll
    for (int k = 0; k < 8; ++k)
      r[k] = (__bf16)xs[(size_t)(c * 256 + s0 + k) * 4096 + h * 64 + p];
    *reinterpret_cast<bf16x8*>(&xsT[p * 264 + s0]) = r;
  }
  __syncthreads();

  const int l1 = w * 32 + (lane & 15);
  const int l2 = l1 + 16;
  const int kcol = (lane >> 4) * 8;
  const float dA1 = dAL[l1], dA2 = dAL[l2];
  const float* CBr1 = CB + ((size_t)(c * 256) + l1) * 256;
  const float* CBr2 = CB + ((size_t)(c * 256) + l2) * 256;
  f32x4 acc[2][4] = {};

  // ---- Y_diag off-diagonal j-blocks (s fully below the diagonal)
  for (int j = 0; j < w; ++j) {
    const int s0 = j * 32 + kcol;
    float cb1[8], cb2[8];
    *reinterpret_cast<float4*>(&cb1[0]) = *reinterpret_cast<const float4*>(CBr1 + s0);
    *reinterpret_cast<float4*>(&cb1[4]) = *reinterpret_cast<const float4*>(CBr1 + s0 + 4);
    *reinterpret_cast<float4*>(&cb2[0]) = *reinterpret_cast<const float4*>(CBr2 + s0);
    *reinterpret_cast<float4*>(&cb2[4]) = *reinterpret_cast<const float4*>(CBr2 + s0 + 4);
    const float a = dAL[j * 32 + 31];
    const float u1 = __expf(dA1 - a), u2 = __expf(dA2 - a);
    float m1[8], m2[8];
#pragma unroll
    for (int t = 0; t < 8; ++t) {
      const float uv = vdt[s0 + t];
      m1[t] = cb1[t] * (u1 * uv);
      m2[t] = cb2[t] * (u2 * uv);
    }
    bf16x8 a1 = pack8(m1), a2 = pack8(m2);
#pragma unroll
    for (int nf = 0; nf < 4; ++nf) {
      bf16x8 bv = *reinterpret_cast<const bf16x8*>(
          &xsT[(nf * 16 + (lane & 15)) * 264 + j * 32 + kcol]);
      acc[0][nf] = __builtin_amdgcn_mfma_f32_16x16x32_bf16(a1, bv, acc[0][nf], 0, 0, 0);
      acc[1][nf] = __builtin_amdgcn_mfma_f32_16x16x32_bf16(a2, bv, acc[1][nf], 0, 0, 0);
    }
  }
  // ---- Y_diag diagonal j-block (j == w): direct exp + triangular select
  {
    const int s0 = w * 32 + kcol;
    float cb1[8], cb2[8];
    *reinterpret_cast<float4*>(&cb1[0]) = *reinterpret_cast<const float4*>(CBr1 + s0);
    *reinterpret_cast<float4*>(&cb1[4]) = *reinterpret_cast<const float4*>(CBr1 + s0 + 4);
    *reinterpret_cast<float4*>(&cb2[0]) = *reinterpret_cast<const float4*>(CBr2 + s0);
    *reinterpret_cast<float4*>(&cb2[4]) = *reinterpret_cast<const float4*>(CBr2 + s0 + 4);
    float m1[8], m2[8];
#pragma unroll
    for (int t = 0; t < 8; ++t) {
      const int s = s0 + t;
      const float e1 = __expf(fminf(dA1 - dAL[s], 0.0f)) * dtL[s];
      const float e2 = __expf(fminf(dA2 - dAL[s], 0.0f)) * dtL[s];
      m1[t] = (s <= l1) ? cb1[t] * e1 : 0.0f;
      m2[t] = (s <= l2) ? cb2[t] * e2 : 0.0f;
    }
    bf16x8 a1 = pack8(m1), a2 = pack8(m2);
#pragma unroll
    for (int nf = 0; nf < 4; ++nf) {
      bf16x8 bv = *reinterpret_cast<const bf16x8*>(
          &xsT[(nf * 16 + (lane & 15)) * 264 + w * 32 + kcol]);
      acc[0][nf] = __builtin_amdgcn_mfma_f32_16x16x32_bf16(a1, bv, acc[0][nf], 0, 0, 0);
      acc[1][nf] = __builtin_amdgcn_mfma_f32_16x16x32_bf16(a2, bv, acc[1][nf], 0, 0, 0);
    }
  }
  // ---- Y_off: K = 128 (n); A = C[l][n]*exp(dAl), B = prev[p][n] bf16 global
  {
    const float eA1 = __expf(dA1), eA2 = __expf(dA2);
    const float* Cr1 = BC + ((size_t)(c * 256) + l1) * 256 + 128;
    const float* Cr2 = BC + ((size_t)(c * 256) + l2) * 256 + 128;
    const unsigned short* pv = prevb + (size_t)bx * 8192;
#pragma unroll
    for (int q = 0; q < 4; ++q) {
      const int n0 = q * 32 + kcol;
      float c1[8], c2[8];
      *reinterpret_cast<float4*>(&c1[0]) = *reinterpret_cast<const float4*>(Cr1 + n0);
      *reinterpret_cast<float4*>(&c1[4]) = *reinterpret_cast<const float4*>(Cr1 + n0 + 4);
      *reinterpret_cast<float4*>(&c2[0]) = *reinterpret_cast<const float4*>(Cr2 + n0);
      *reinterpret_cast<float4*>(&c2[4]) = *reinterpret_cast<const float4*>(Cr2 + n0 + 4);
      float m1[8], m2[8];
#pragma unroll
      for (int t = 0; t < 8; ++t) { m1[t] = c1[t] * eA1; m2[t] = c2[t] * eA2; }
      bf16x8 a1 = pack8(m1), a2 = pack8(m2);
#pragma unroll
      for (int nf = 0; nf < 4; ++nf) {
        bf16x8 bv = *reinterpret_cast<const bf16x8*>(
            pv + (size_t)(nf * 16 + (lane & 15)) * 128 + n0);
        acc[0][nf] = __builtin_amdgcn_mfma_f32_16x16x32_bf16(a1, bv, acc[0][nf], 0, 0, 0);
        acc[1][nf] = __builtin_amdgcn_mfma_f32_16x16x32_bf16(a2, bv, acc[1][nf], 0, 0, 0);
      }
    }
  }
  // ---- epilogue: y = acc + D*xs
  const float Dh = Dp[h];
  const int rb = (lane >> 4) * 4;
#pragma unroll
  for (int mf = 0; mf < 2; ++mf) {
#pragma unroll
    for (int nf = 0; nf < 4; ++nf) {
      const int p = nf * 16 + (lane & 15);
#pragma unroll
      for (int v = 0; v < 4; ++v) {
        const int l = w * 32 + mf * 16 + rb + v;
        y[(size_t)(c * 256 + l) * 4096 + h * 64 + p] =
            acc[mf][nf][v] + Dh * b2f(xsT[p * 264 + l]);
      }
    }
  }
}

// ---------------------------------------------------------------------------
// gated RMSNorm: y2 = rmsnorm(y * silu(z)) * norm_w  -> bf16
// ---------------------------------------------------------------------------
__global__ __launch_bounds__(256) void gated_rmsnorm(
    const float* __restrict__ y, const float* __restrict__ proj,
    const float* __restrict__ nw, unsigned short* __restrict__ y2) {
  const int row = blockIdx.x;
  const float* yr = y + (size_t)row * 4096;
  const float* zr = proj + (size_t)row * 8512;    // z = cols 0..4095
  const int base = threadIdx.x * 16;
  float g[16];
  float ss = 0.0f;
#pragma unroll
  for (int j = 0; j < 16; j += 4) {
    const float4 yv = *reinterpret_cast<const float4*>(yr + base + j);
    const float4 zv = *reinterpret_cast<const float4*>(zr + base + j);
    const float a0 = yv.x * (zv.x / (1.0f + expf(-zv.x)));
    const float a1 = yv.y * (zv.y / (1.0f + expf(-zv.y)));
    const float a2 = yv.z * (zv.z / (1.0f + expf(-zv.z)));
    const float a3 = yv.w * (zv.w / (1.0f + expf(-zv.w)));
    g[j] = a0; g[j+1] = a1; g[j+2] = a2; g[j+3] = a3;
    ss += a0*a0 + a1*a1 + a2*a2 + a3*a3;
  }
  __shared__ float red[4];
#pragma unroll
  for (int off = 32; off > 0; off >>= 1) ss += __shfl_xor(ss, off);
  if ((threadIdx.x & 63) == 0) red[threadIdx.x >> 6] = ss;
  __syncthreads();
  ss = red[0] + red[1] + red[2] + red[3];
  const float scale = rsqrtf(ss * (1.0f / 4096.0f) + 1e-5f);
#pragma unroll
  for (int j = 0; j < 16; j += 4) {
    ushort4 o;
    o.x = f2b(g[j]   * scale * nw[base + j]);
    o.y = f2b(g[j+1] * scale * nw[base + j + 1]);
    o.z = f2b(g[j+2] * scale * nw[base + j + 2]);
    o.w = f2b(g[j+3] * scale * nw[base + j + 3]);
    *reinterpret_cast<ushort4*>(y2 + (size_t)row * 4096 + base + j) = o;
  }
}

// ---------------------------------------------------------------------------
extern "C" void kernel_launch(void* const* d_in, const int* in_sizes, int n_in,
                              void* d_out, int out_size, void* d_ws, size_t ws_size,
                              hipStream_t stream) {
  const float* x       = (const float*)d_in[0];
  const float* rms_w   = (const float*)d_in[1];
  const float* W_in    = (const float*)d_in[2];
  const float* conv_w  = (const float*)d_in[3];
  const float* conv_b  = (const float*)d_in[4];
  const float* dt_bias = (const float*)d_in[5];
  const float* A_log   = (const float*)d_in[6];
  const float* Dp      = (const float*)d_in[7];
  const float* norm_w  = (const float*)d_in[8];
  const float* W_out   = (const float*)d_in[9];
  float* out = (float*)d_out;

  char* ws = (char*)d_ws;
  size_t off = 0;
  auto alloc = [&](size_t bytes) {
    void* p = ws + off;
    off += (bytes + 255) & ~(size_t)255;
    return p;
  };
  unsigned short* Wb_in  = (unsigned short*)alloc((size_t)8576 * 2048 * 2);
  unsigned short* Wb_out = (unsigned short*)alloc((size_t)2048 * 4096 * 2);
  unsigned short* hbuf   = (unsigned short*)alloc((size_t)2048 * 2048 * 2);
  float* proj   = (float*)alloc((size_t)2048 * 8512 * 4);
  float* xsbuf  = (float*)alloc((size_t)2048 * 4096 * 4);   // xs, then y (in-place)
  float* BCbuf  = (float*)alloc((size_t)2048 * 256 * 4);
  unsigned short* BTb = (unsigned short*)alloc((size_t)8 * 128 * 256 * 2);
  float* dtcbuf = (float*)alloc((size_t)2048 * 64 * 4);
  float* dAcbuf = (float*)alloc((size_t)512 * 256 * 4);
  float* cdec   = (float*)alloc((size_t)512 * 4);
  float* CBbuf  = (float*)alloc((size_t)8 * 256 * 256 * 4);
  float* statesT = (float*)alloc((size_t)512 * 64 * 128 * 4);
  unsigned short* y2 = Wb_in;              // dead after in_proj GEMM
  unsigned short* prevb = hbuf;            // dead after in_proj GEMM (8 MB exact)

  (void)in_sizes; (void)n_in; (void)out_size; (void)ws_size;

  // weight conversion (every call; no caching allowed)
  f32_to_bf16_pad<<<(8576 * 2048 / 4 + 255) / 256, 256, 0, stream>>>(
      W_in, Wb_in, (long)8512 * 2048, (long)8576 * 2048);
  f32_to_bf16_pad<<<(2048 * 4096 / 4 + 255) / 256, 256, 0, stream>>>(
      W_out, Wb_out, (long)2048 * 4096, (long)2048 * 4096);

  // 1. input RMSNorm -> bf16
  rmsnorm_in<<<2048, 256, 0, stream>>>(x, rms_w, hbuf);

  // 2. in_proj: proj[2048,8512] = h @ W_in^T
  gemm_bt<false><<<16 * 67, 256, 0, stream>>>(hbuf, Wb_in, proj, nullptr,
                                              2048, 8512, 8512, 16, 67, 4);

  // 3. conv + SiLU + softplus(dt); emits BC fp32 + BTb bf16
  conv_silu_dt<<<dim3(18, 128), 256, 0, stream>>>(proj, conv_w, conv_b, dt_bias,
                                                  xsbuf, BCbuf, BTb, dtcbuf);

  // 4. per-(chunk,head) cumsum of dt*A; chunk decay
  scan_dA<<<512, 256, 0, stream>>>(dtcbuf, A_log, dAcbuf, cdec);

  // 5. CB = C @ B^T per chunk (row-major)
  cb_k<<<2048, 256, 0, stream>>>(BCbuf, CBbuf);

  // 6. MFMA chunk states
  ssd_states<<<512, 512, 0, stream>>>(xsbuf, BTb, dtcbuf, dAcbuf, statesT);

  // 7. inter-chunk recurrence -> prev states (bf16)
  ssd_scan<<<2048, 256, 0, stream>>>(statesT, prevb, cdec);

  // 8. MFMA Y_diag + Y_off + D*xs -> y (in-place over xs)
  ssd_diag_off<<<512, 512, 0, stream>>>(xsbuf, BCbuf, dtcbuf, dAcbuf, CBbuf,
                                        prevb, Dp, xsbuf);

  // 9. gated RMSNorm -> bf16
  gated_rmsnorm<<<2048, 256, 0, stream>>>(xsbuf, proj, norm_w, y2);

  // 10. out_proj + residual -> d_out
  gemm_bt64<true><<<32 * 16, 256, 0, stream>>>(y2, Wb_out, out, x,
                                               4096, 2048, 2048, 32, 16, 4);
}

// Round 6
// 349.579 us; speedup vs baseline: 1.5257x; 1.0661x over previous
//
#include <hip/hip_runtime.h>
#include <stdint.h>

// ---------------------------------------------------------------------------
// FalconMamba2 SSM decoder layer, MI355X (gfx950) — round 6
// Round-5 + counted-vmcnt double-buffered GEMM pipeline (raw s_barrier, no
// vmcnt(0) drain in steady state) + both-sides LDS XOR swizzle + setprio.
// SSD (MFMA) kernels unchanged from round 5.
// ---------------------------------------------------------------------------

typedef __bf16 bf16x8 __attribute__((ext_vector_type(8)));
typedef float  f32x4  __attribute__((ext_vector_type(4)));

#define DEVFN __device__ __forceinline__

DEVFN unsigned short f2b(float f) {
  uint32_t u = __builtin_bit_cast(uint32_t, f);
  u += 0x7fffu + ((u >> 16) & 1u);          // round-to-nearest-even
  return (unsigned short)(u >> 16);
}
DEVFN float b2f(unsigned short u) {
  uint32_t x = (uint32_t)u << 16;
  return __builtin_bit_cast(float, x);
}
DEVFN bf16x8 pack8(const float (&m)[8]) {
  bf16x8 r;
#pragma unroll
  for (int t = 0; t < 8; ++t) r[t] = (__bf16)m[t];
  return r;
}

// bijective XCD swizzle (m204) + GROUP-major supertiling
DEVFN void tile_map(int bid, int nwg, int nm, int nn, int grp, int& mt, int& nt) {
  const int q = nwg >> 3, r = nwg & 7;
  const int xcd = bid & 7, lid = bid >> 3;
  const int wg = (xcd < r ? xcd * (q + 1) : r * (q + 1) + (xcd - r) * q) + lid;
  const int per = grp * nn;
  const int g = wg / per;
  const int rem = wg - g * per;
  const int lim = nm - g * grp;
  const int gm = lim < grp ? lim : grp;
  mt = g * grp + rem % gm;
  nt = rem / gm;
}

// ---------------------------------------------------------------------------
__global__ void f32_to_bf16_pad(const float* __restrict__ src,
                                unsigned short* __restrict__ dst,
                                long srcElems, long dstElems) {
  const long i = ((long)blockIdx.x * 256 + threadIdx.x) * 4;
  if (i >= dstElems) return;
  ushort4 o;
  if (i < srcElems) {
    float4 v = *reinterpret_cast<const float4*>(src + i);
    o.x = f2b(v.x); o.y = f2b(v.y); o.z = f2b(v.z); o.w = f2b(v.w);
  } else {
    o.x = 0; o.y = 0; o.z = 0; o.w = 0;
  }
  *reinterpret_cast<ushort4*>(dst + i) = o;
}

// ---------------------------------------------------------------------------
__global__ __launch_bounds__(256) void rmsnorm_in(
    const float* __restrict__ x, const float* __restrict__ w,
    unsigned short* __restrict__ h) {
  const int row = blockIdx.x;
  const float* xr = x + (size_t)row * 2048;
  const int base = threadIdx.x * 8;
  float4 v0 = *reinterpret_cast<const float4*>(xr + base);
  float4 v1 = *reinterpret_cast<const float4*>(xr + base + 4);
  float ss = v0.x*v0.x + v0.y*v0.y + v0.z*v0.z + v0.w*v0.w
           + v1.x*v1.x + v1.y*v1.y + v1.z*v1.z + v1.w*v1.w;
  __shared__ float red[4];
#pragma unroll
  for (int off = 32; off > 0; off >>= 1) ss += __shfl_xor(ss, off);
  if ((threadIdx.x & 63) == 0) red[threadIdx.x >> 6] = ss;
  __syncthreads();
  ss = red[0] + red[1] + red[2] + red[3];
  const float scale = rsqrtf(ss * (1.0f / 2048.0f) + 1e-5f);
  float vals[8] = {v0.x, v0.y, v0.z, v0.w, v1.x, v1.y, v1.z, v1.w};
  unsigned short o[8];
#pragma unroll
  for (int j = 0; j < 8; ++j) o[j] = f2b(vals[j] * scale * w[base + j]);
  ushort4 a, b;
  a.x = o[0]; a.y = o[1]; a.z = o[2]; a.w = o[3];
  b.x = o[4]; b.y = o[5]; b.z = o[6]; b.w = o[7];
  *reinterpret_cast<ushort4*>(h + (size_t)row * 2048 + base)     = a;
  *reinterpret_cast<ushort4*>(h + (size_t)row * 2048 + base + 4) = b;
}

// ---------------------------------------------------------------------------
// Pipelined bf16 GEMM, C[M,N] = A[M,K] @ B[N,K]^T (+res). Tile BM x 128,
// BK=64, 4 waves (2x2). Double-buffered LDS, counted vmcnt (never 0 in
// steady state), raw s_barrier, XOR-swizzled LDS chunks (both sides).
// MF = BM/32 = A frags per wave = A staging loads per thread.
// ---------------------------------------------------------------------------
template<int BM, bool RES>
__global__ __launch_bounds__(256, 2) void gemm_pipe(
    const unsigned short* __restrict__ A, const unsigned short* __restrict__ B,
    float* __restrict__ C, const float* __restrict__ res,
    int K, int Nc, int ldc, int nm, int nn, int grp) {
  constexpr int MF = BM / 32;
  __shared__ __align__(16) unsigned short As[2][BM * 64];
  __shared__ __align__(16) unsigned short Bs[2][128 * 64];
  int mt, nt;
  tile_map(blockIdx.x, nm * nn, nm, nn, grp, mt, nt);
  const int m0 = mt * BM;
  const int n0 = nt * 128;
  const int tid  = threadIdx.x;
  const int wid  = tid >> 6;
  const int lane = tid & 63;
  const int wm   = (wid >> 1) * (BM / 2);
  const int wn   = (wid & 1) * 64;
  const int lrow = lane & 15;
  const int lkc  = lane >> 4;             // k-chunk 0..3 (8 elems each)

  // stage: LDS slot (row r, chunk cc) holds global k-chunk cc^(r&7)
  auto stageA = [&](int buf, int k0) {
#pragma unroll
    for (int i = 0; i < MF; ++i) {
      const int ci = tid + i * 256;
      const int r = ci >> 3, cc = ci & 7;
      const int gc = cc ^ (r & 7);
      __builtin_amdgcn_global_load_lds(
          (const __attribute__((address_space(1))) void*)(A + (size_t)(m0 + r) * K + k0 + gc * 8),
          (__attribute__((address_space(3))) void*)(&As[buf][ci * 8]), 16, 0, 0);
    }
  };
  auto stageB = [&](int buf, int k0) {
#pragma unroll
    for (int i = 0; i < 4; ++i) {
      const int ci = tid + i * 256;
      const int r = ci >> 3, cc = ci & 7;
      const int gc = cc ^ (r & 7);
      __builtin_amdgcn_global_load_lds(
          (const __attribute__((address_space(1))) void*)(B + (size_t)(n0 + r) * K + k0 + gc * 8),
          (__attribute__((address_space(3))) void*)(&Bs[buf][ci * 8]), 16, 0, 0);
    }
  };

  f32x4 acc[MF][4] = {};
  const int nsteps = K >> 6;

  stageA(0, 0); stageB(0, 0);
  if (nsteps > 1) { stageA(1, 64); stageB(1, 64); }
  if (nsteps > 1) asm volatile("s_waitcnt vmcnt(%0)" :: "n"(MF + 4) : "memory");
  else            asm volatile("s_waitcnt vmcnt(0)" ::: "memory");
  __builtin_amdgcn_s_barrier();
  __builtin_amdgcn_sched_barrier(0);

  int cur = 0;
  for (int t = 0; t < nsteps; ++t) {
    bf16x8 af[MF][2], bf[4][2];
#pragma unroll
    for (int m = 0; m < MF; ++m)
#pragma unroll
      for (int kk = 0; kk < 2; ++kk) {
        const int row = wm + m * 16 + lrow;
        const int c = kk * 4 + lkc;
        af[m][kk] = *reinterpret_cast<const bf16x8*>(
            &As[cur][row * 64 + ((c ^ (row & 7)) * 8)]);
      }
#pragma unroll
    for (int n = 0; n < 4; ++n)
#pragma unroll
      for (int kk = 0; kk < 2; ++kk) {
        const int row = wn + n * 16 + lrow;
        const int c = kk * 4 + lkc;
        bf[n][kk] = *reinterpret_cast<const bf16x8*>(
            &Bs[cur][row * 64 + ((c ^ (row & 7)) * 8)]);
      }
    // all frag ds_reads must complete (into regs) before anyone overwrites cur
    asm volatile("s_waitcnt lgkmcnt(0)" ::: "memory");
    __builtin_amdgcn_sched_barrier(0);
    __builtin_amdgcn_s_barrier();
    if (t + 2 < nsteps) { stageA(cur, (t + 2) * 64); stageB(cur, (t + 2) * 64); }
    __builtin_amdgcn_s_setprio(1);
#pragma unroll
    for (int kk = 0; kk < 2; ++kk)
#pragma unroll
      for (int m = 0; m < MF; ++m)
#pragma unroll
        for (int n = 0; n < 4; ++n)
          acc[m][n] = __builtin_amdgcn_mfma_f32_16x16x32_bf16(af[m][kk], bf[n][kk], acc[m][n], 0, 0, 0);
    __builtin_amdgcn_s_setprio(0);
    if (t + 1 < nsteps) {
      // counted wait: t+1's MF+4 loads done; t+2's (if staged) stay in flight
      if (t + 2 < nsteps) asm volatile("s_waitcnt vmcnt(%0)" :: "n"(MF + 4) : "memory");
      else                asm volatile("s_waitcnt vmcnt(0)" ::: "memory");
      __builtin_amdgcn_sched_barrier(0);
      __builtin_amdgcn_s_barrier();
    }
    cur ^= 1;
  }

  // C/D layout: col = lane&15, row = (lane>>4)*4 + reg  [m89/m91 verified]
#pragma unroll
  for (int m = 0; m < MF; ++m) {
#pragma unroll
    for (int n = 0; n < 4; ++n) {
      const int col = n0 + wn + n * 16 + lrow;
      if (col < Nc) {
#pragma unroll
        for (int v = 0; v < 4; ++v) {
          const int row = m0 + wm + m * 16 + (lane >> 4) * 4 + v;
          const size_t idx = (size_t)row * ldc + col;
          float val = acc[m][n][v];
          if (RES) val += res[idx];
          C[idx] = val;
        }
      }
    }
  }
}

// ---------------------------------------------------------------------------
// causal depthwise conv(K=4) + SiLU; softplus(dt+bias). 16 l per thread.
// Emits BC fp32 and BTb bf16 ([c][n][s], B transposed) for MFMA states.
// ---------------------------------------------------------------------------
__global__ __launch_bounds__(256) void conv_silu_dt(
    const float* __restrict__ proj, const float* __restrict__ conv_w,
    const float* __restrict__ conv_b, const float* __restrict__ dt_bias,
    float* __restrict__ xs, float* __restrict__ BC,
    unsigned short* __restrict__ BTb, float* __restrict__ dtc) {
  const int cch = blockIdx.x * 256 + threadIdx.x;
  const int l0 = blockIdx.y * 16;
  if (cch < 4352) {
    const float4 w = *reinterpret_cast<const float4*>(conv_w + (size_t)cch * 4);
    const float b = conv_b[cch];
    const float* pcol = proj + 4096 + cch;
    float w0, w1, w2;
    w0 = (l0 >= 3) ? pcol[(size_t)(l0 - 3) * 8512] : 0.0f;
    w1 = (l0 >= 2) ? pcol[(size_t)(l0 - 2) * 8512] : 0.0f;
    w2 = (l0 >= 1) ? pcol[(size_t)(l0 - 1) * 8512] : 0.0f;
#pragma unroll
    for (int i = 0; i < 16; ++i) {
      const int l = l0 + i;
      const float cur = pcol[(size_t)l * 8512];
      float acc = b + w0 * w.x + w1 * w.y + w2 * w.z + cur * w.w;
      w0 = w1; w1 = w2; w2 = cur;
      acc = acc / (1.0f + __expf(-acc));   // silu
      if (cch < 4096) {
        xs[(size_t)l * 4096 + cch] = acc;
      } else {
        BC[(size_t)l * 256 + (cch - 4096)] = acc;
        if (cch < 4224) {                   // B channels -> transposed bf16
          const int n = cch - 4096;
          BTb[((size_t)((l >> 8) * 128) + n) * 256 + (l & 255)] = f2b(acc);
        }
      }
    }
  } else if (cch < 4416) {
    const int hh = cch - 4352;
    const float bias = dt_bias[hh];
#pragma unroll
    for (int i = 0; i < 16; ++i) {
      const int l = l0 + i;
      const float v = proj[(size_t)l * 8512 + 8448 + hh] + bias;
      dtc[(size_t)l * 64 + hh] = (v > 20.0f) ? v : log1pf(expf(v));
    }
  }
}

// ---------------------------------------------------------------------------
__global__ __launch_bounds__(256) void scan_dA(
    const float* __restrict__ dtc, const float* __restrict__ A_log,
    float* __restrict__ dAc, float* __restrict__ cdec) {
  const int bx = blockIdx.x;              // c*64 + h
  const int c = bx >> 6, h = bx & 63;
  const int l = threadIdx.x;
  __shared__ float buf[256];
  const float Ah = -expf(A_log[h]);
  buf[l] = dtc[(size_t)(c * 256 + l) * 64 + h] * Ah;
  __syncthreads();
  for (int off = 1; off < 256; off <<= 1) {
    const float t = (l >= off) ? buf[l - off] : 0.0f;
    __syncthreads();
    buf[l] += t;
    __syncthreads();
  }
  dAc[(size_t)bx * 256 + l] = buf[l];
  if (l == 255) cdec[bx] = expf(buf[255]);
}

// ---------------------------------------------------------------------------
// CB[c][l][s] = sum_n C[c,l,n] * B[c,s,n]   (row-major, G=1 head-shared)
// ---------------------------------------------------------------------------
__global__ __launch_bounds__(256) void cb_k(const float* __restrict__ BC,
                                            float* __restrict__ CB) {
  const int gl = blockIdx.x;              // c*256 + l
  const int c = gl >> 8;
  const int s = threadIdx.x;
  __shared__ float Crow[128];
  if (threadIdx.x < 128) Crow[threadIdx.x] = BC[(size_t)gl * 256 + 128 + threadIdx.x];
  __syncthreads();
  const float* Br = BC + (size_t)(c * 256 + s) * 256;
  float acc = 0.0f;
#pragma unroll 4
  for (int n = 0; n < 128; ++n) acc += Crow[n] * Br[n];
  CB[(size_t)gl * 256 + s] = acc;
}

// ---------------------------------------------------------------------------
// MFMA states: statesT[c][h][p][n] = sum_s (w*xs)[s,p] * B[s,n]
// ---------------------------------------------------------------------------
__global__ __launch_bounds__(512) void ssd_states(
    const float* __restrict__ xs, const unsigned short* __restrict__ BTb,
    const float* __restrict__ dtc, const float* __restrict__ dAc,
    float* __restrict__ statesT) {
  const int bx = blockIdx.x;              // c*64 + h
  const int c = bx >> 6, h = bx & 63;
  __shared__ __align__(16) unsigned short xwT[64 * 264];   // [p][s], +8 pad
  __shared__ float dAL[256], wLs[256];
  const int tid = threadIdx.x;
  const int lane = tid & 63;
  const int w = tid >> 6;

  if (tid < 256) dAL[tid] = dAc[(size_t)bx * 256 + tid];
  else           wLs[tid - 256] = dtc[(size_t)(c * 256 + (tid - 256)) * 64 + h];
  __syncthreads();
  if (tid < 256) wLs[tid] = __expf(dAL[255] - dAL[tid]) * wLs[tid];
  __syncthreads();
#pragma unroll
  for (int it = 0; it < 4; ++it) {
    const int gid = it * 512 + tid;
    const int p = gid & 63;
    const int s0 = (gid >> 6) * 8;
    bf16x8 r;
#pragma unroll
    for (int k = 0; k < 8; ++k)
      r[k] = (__bf16)(xs[(size_t)(c * 256 + s0 + k) * 4096 + h * 64 + p] * wLs[s0 + k]);
    *reinterpret_cast<bf16x8*>(&xwT[p * 264 + s0]) = r;
  }
  __syncthreads();

  const int pb = (w & 3) * 16;
  const int nb = (w >> 2) * 64;
  const int kcol = (lane >> 4) * 8;
  f32x4 acc[4] = {};
  for (int k = 0; k < 8; ++k) {
    bf16x8 av = *reinterpret_cast<const bf16x8*>(&xwT[(pb + (lane & 15)) * 264 + k * 32 + kcol]);
#pragma unroll
    for (int nf = 0; nf < 4; ++nf) {
      bf16x8 bv = *reinterpret_cast<const bf16x8*>(
          BTb + ((size_t)(c * 128) + nb + nf * 16 + (lane & 15)) * 256 + k * 32 + kcol);
      acc[nf] = __builtin_amdgcn_mfma_f32_16x16x32_bf16(av, bv, acc[nf], 0, 0, 0);
    }
  }
  const int rb = (lane >> 4) * 4;
#pragma unroll
  for (int nf = 0; nf < 4; ++nf) {
    const int n = nb + nf * 16 + (lane & 15);
#pragma unroll
    for (int v = 0; v < 4; ++v) {
      const int p = pb + rb + v;
      statesT[(size_t)bx * 8192 + p * 128 + n] = acc[nf][v];
    }
  }
}

// ---------------------------------------------------------------------------
// inter-chunk scan: emits prev-state (BEFORE chunk) as bf16 [c][h][p][n]
// ---------------------------------------------------------------------------
__global__ void ssd_scan(const float* __restrict__ statesT,
                         unsigned short* __restrict__ prevb,
                         const float* __restrict__ cdec) {
  const int i = blockIdx.x * 256 + threadIdx.x;   // < 64*8192
  const int h = i >> 13;
  const int r = i & 8191;
  float carry = 0.0f;
#pragma unroll
  for (int c = 0; c < 8; ++c) {
    const size_t idx = ((size_t)(c * 64 + h)) * 8192 + r;
    const float st = statesT[idx];
    prevb[idx] = f2b(carry);
    carry = carry * cdec[c * 64 + h] + st;
  }
}

// ---------------------------------------------------------------------------
// MFMA Y_diag + Y_off + D*xs -> y. block = (c,h), 512 thr, 8 waves.
// ---------------------------------------------------------------------------
__global__ __launch_bounds__(512) void ssd_diag_off(
    const float* xs, const float* __restrict__ BC,
    const float* __restrict__ dtc, const float* __restrict__ dAc,
    const float* __restrict__ CB, const unsigned short* __restrict__ prevb,
    const float* __restrict__ Dp, float* y) {
  const int bx = blockIdx.x;              // c*64 + h
  const int c = bx >> 6, h = bx & 63;
  __shared__ __align__(16) unsigned short xsT[64 * 264];   // [p][s], +8 pad
  __shared__ float dAL[256], dtL[256], vdt[256];
  const int tid = threadIdx.x;
  const int lane = tid & 63;
  const int w = tid >> 6;

  if (tid < 256) {
    dAL[tid] = dAc[(size_t)bx * 256 + tid];
    dtL[tid] = dtc[(size_t)(c * 256 + tid) * 64 + h];
  }
  __syncthreads();
  if (tid < 256) vdt[tid] = __expf(dAL[tid | 31] - dAL[tid]) * dtL[tid];
#pragma unroll
  for (int it = 0; it < 4; ++it) {
    const int gid = it * 512 + tid;
    const int p = gid & 63;
    const int s0 = (gid >> 6) * 8;
    bf16x8 r;
#pragma unroll
    for (int k = 0; k < 8; ++k)
      r[k] = (__bf16)xs[(size_t)(c * 256 + s0 + k) * 4096 + h * 64 + p];
    *reinterpret_cast<bf16x8*>(&xsT[p * 264 + s0]) = r;
  }
  __syncthreads();

  const int l1 = w * 32 + (lane & 15);
  const int l2 = l1 + 16;
  const int kcol = (lane >> 4) * 8;
  const float dA1 = dAL[l1], dA2 = dAL[l2];
  const float* CBr1 = CB + ((size_t)(c * 256) + l1) * 256;
  const float* CBr2 = CB + ((size_t)(c * 256) + l2) * 256;
  f32x4 acc[2][4] = {};

  // ---- Y_diag off-diagonal j-blocks
  for (int j = 0; j < w; ++j) {
    const int s0 = j * 32 + kcol;
    float cb1[8], cb2[8];
    *reinterpret_cast<float4*>(&cb1[0]) = *reinterpret_cast<const float4*>(CBr1 + s0);
    *reinterpret_cast<float4*>(&cb1[4]) = *reinterpret_cast<const float4*>(CBr1 + s0 + 4);
    *reinterpret_cast<float4*>(&cb2[0]) = *reinterpret_cast<const float4*>(CBr2 + s0);
    *reinterpret_cast<float4*>(&cb2[4]) = *reinterpret_cast<const float4*>(CBr2 + s0 + 4);
    const float a = dAL[j * 32 + 31];
    const float u1 = __expf(dA1 - a), u2 = __expf(dA2 - a);
    float m1[8], m2[8];
#pragma unroll
    for (int t = 0; t < 8; ++t) {
      const float uv = vdt[s0 + t];
      m1[t] = cb1[t] * (u1 * uv);
      m2[t] = cb2[t] * (u2 * uv);
    }
    bf16x8 a1 = pack8(m1), a2 = pack8(m2);
#pragma unroll
    for (int nf = 0; nf < 4; ++nf) {
      bf16x8 bv = *reinterpret_cast<const bf16x8*>(
          &xsT[(nf * 16 + (lane & 15)) * 264 + j * 32 + kcol]);
      acc[0][nf] = __builtin_amdgcn_mfma_f32_16x16x32_bf16(a1, bv, acc[0][nf], 0, 0, 0);
      acc[1][nf] = __builtin_amdgcn_mfma_f32_16x16x32_bf16(a2, bv, acc[1][nf], 0, 0, 0);
    }
  }
  // ---- diagonal block: direct exp + triangular select
  {
    const int s0 = w * 32 + kcol;
    float cb1[8], cb2[8];
    *reinterpret_cast<float4*>(&cb1[0]) = *reinterpret_cast<const float4*>(CBr1 + s0);
    *reinterpret_cast<float4*>(&cb1[4]) = *reinterpret_cast<const float4*>(CBr1 + s0 + 4);
    *reinterpret_cast<float4*>(&cb2[0]) = *reinterpret_cast<const float4*>(CBr2 + s0);
    *reinterpret_cast<float4*>(&cb2[4]) = *reinterpret_cast<const float4*>(CBr2 + s0 + 4);
    float m1[8], m2[8];
#pragma unroll
    for (int t = 0; t < 8; ++t) {
      const int s = s0 + t;
      const float e1 = __expf(fminf(dA1 - dAL[s], 0.0f)) * dtL[s];
      const float e2 = __expf(fminf(dA2 - dAL[s], 0.0f)) * dtL[s];
      m1[t] = (s <= l1) ? cb1[t] * e1 : 0.0f;
      m2[t] = (s <= l2) ? cb2[t] * e2 : 0.0f;
    }
    bf16x8 a1 = pack8(m1), a2 = pack8(m2);
#pragma unroll
    for (int nf = 0; nf < 4; ++nf) {
      bf16x8 bv = *reinterpret_cast<const bf16x8*>(
          &xsT[(nf * 16 + (lane & 15)) * 264 + w * 32 + kcol]);
      acc[0][nf] = __builtin_amdgcn_mfma_f32_16x16x32_bf16(a1, bv, acc[0][nf], 0, 0, 0);
      acc[1][nf] = __builtin_amdgcn_mfma_f32_16x16x32_bf16(a2, bv, acc[1][nf], 0, 0, 0);
    }
  }
  // ---- Y_off: A = C[l][n]*exp(dAl), B = prev[p][n] bf16 global
  {
    const float eA1 = __expf(dA1), eA2 = __expf(dA2);
    const float* Cr1 = BC + ((size_t)(c * 256) + l1) * 256 + 128;
    const float* Cr2 = BC + ((size_t)(c * 256) + l2) * 256 + 128;
    const unsigned short* pv = prevb + (size_t)bx * 8192;
#pragma unroll
    for (int q = 0; q < 4; ++q) {
      const int n0 = q * 32 + kcol;
      float c1[8], c2[8];
      *reinterpret_cast<float4*>(&c1[0]) = *reinterpret_cast<const float4*>(Cr1 + n0);
      *reinterpret_cast<float4*>(&c1[4]) = *reinterpret_cast<const float4*>(Cr1 + n0 + 4);
      *reinterpret_cast<float4*>(&c2[0]) = *reinterpret_cast<const float4*>(Cr2 + n0);
      *reinterpret_cast<float4*>(&c2[4]) = *reinterpret_cast<const float4*>(Cr2 + n0 + 4);
      float m1[8], m2[8];
#pragma unroll
      for (int t = 0; t < 8; ++t) { m1[t] = c1[t] * eA1; m2[t] = c2[t] * eA2; }
      bf16x8 a1 = pack8(m1), a2 = pack8(m2);
#pragma unroll
      for (int nf = 0; nf < 4; ++nf) {
        bf16x8 bv = *reinterpret_cast<const bf16x8*>(
            pv + (size_t)(nf * 16 + (lane & 15)) * 128 + n0);
        acc[0][nf] = __builtin_amdgcn_mfma_f32_16x16x32_bf16(a1, bv, acc[0][nf], 0, 0, 0);
        acc[1][nf] = __builtin_amdgcn_mfma_f32_16x16x32_bf16(a2, bv, acc[1][nf], 0, 0, 0);
      }
    }
  }
  // ---- epilogue: y = acc + D*xs
  const float Dh = Dp[h];
  const int rb = (lane >> 4) * 4;
#pragma unroll
  for (int mf = 0; mf < 2; ++mf) {
#pragma unroll
    for (int nf = 0; nf < 4; ++nf) {
      const int p = nf * 16 + (lane & 15);
#pragma unroll
      for (int v = 0; v < 4; ++v) {
        const int l = w * 32 + mf * 16 + rb + v;
        y[(size_t)(c * 256 + l) * 4096 + h * 64 + p] =
            acc[mf][nf][v] + Dh * b2f(xsT[p * 264 + l]);
      }
    }
  }
}

// ---------------------------------------------------------------------------
// gated RMSNorm: y2 = rmsnorm(y * silu(z)) * norm_w  -> bf16
// ---------------------------------------------------------------------------
__global__ __launch_bounds__(256) void gated_rmsnorm(
    const float* __restrict__ y, const float* __restrict__ proj,
    const float* __restrict__ nw, unsigned short* __restrict__ y2) {
  const int row = blockIdx.x;
  const float* yr = y + (size_t)row * 4096;
  const float* zr = proj + (size_t)row * 8512;    // z = cols 0..4095
  const int base = threadIdx.x * 16;
  float g[16];
  float ss = 0.0f;
#pragma unroll
  for (int j = 0; j < 16; j += 4) {
    const float4 yv = *reinterpret_cast<const float4*>(yr + base + j);
    const float4 zv = *reinterpret_cast<const float4*>(zr + base + j);
    const float a0 = yv.x * (zv.x / (1.0f + expf(-zv.x)));
    const float a1 = yv.y * (zv.y / (1.0f + expf(-zv.y)));
    const float a2 = yv.z * (zv.z / (1.0f + expf(-zv.z)));
    const float a3 = yv.w * (zv.w / (1.0f + expf(-zv.w)));
    g[j] = a0; g[j+1] = a1; g[j+2] = a2; g[j+3] = a3;
    ss += a0*a0 + a1*a1 + a2*a2 + a3*a3;
  }
  __shared__ float red[4];
#pragma unroll
  for (int off = 32; off > 0; off >>= 1) ss += __shfl_xor(ss, off);
  if ((threadIdx.x & 63) == 0) red[threadIdx.x >> 6] = ss;
  __syncthreads();
  ss = red[0] + red[1] + red[2] + red[3];
  const float scale = rsqrtf(ss * (1.0f / 4096.0f) + 1e-5f);
#pragma unroll
  for (int j = 0; j < 16; j += 4) {
    ushort4 o;
    o.x = f2b(g[j]   * scale * nw[base + j]);
    o.y = f2b(g[j+1] * scale * nw[base + j + 1]);
    o.z = f2b(g[j+2] * scale * nw[base + j + 2]);
    o.w = f2b(g[j+3] * scale * nw[base + j + 3]);
    *reinterpret_cast<ushort4*>(y2 + (size_t)row * 4096 + base + j) = o;
  }
}

// ---------------------------------------------------------------------------
extern "C" void kernel_launch(void* const* d_in, const int* in_sizes, int n_in,
                              void* d_out, int out_size, void* d_ws, size_t ws_size,
                              hipStream_t stream) {
  const float* x       = (const float*)d_in[0];
  const float* rms_w   = (const float*)d_in[1];
  const float* W_in    = (const float*)d_in[2];
  const float* conv_w  = (const float*)d_in[3];
  const float* conv_b  = (const float*)d_in[4];
  const float* dt_bias = (const float*)d_in[5];
  const float* A_log   = (const float*)d_in[6];
  const float* Dp      = (const float*)d_in[7];
  const float* norm_w  = (const float*)d_in[8];
  const float* W_out   = (const float*)d_in[9];
  float* out = (float*)d_out;

  char* ws = (char*)d_ws;
  size_t off = 0;
  auto alloc = [&](size_t bytes) {
    void* p = ws + off;
    off += (bytes + 255) & ~(size_t)255;
    return p;
  };
  unsigned short* Wb_in  = (unsigned short*)alloc((size_t)8576 * 2048 * 2);
  unsigned short* Wb_out = (unsigned short*)alloc((size_t)2048 * 4096 * 2);
  unsigned short* hbuf   = (unsigned short*)alloc((size_t)2048 * 2048 * 2);
  float* proj   = (float*)alloc((size_t)2048 * 8512 * 4);
  float* xsbuf  = (float*)alloc((size_t)2048 * 4096 * 4);   // xs, then y (in-place)
  float* BCbuf  = (float*)alloc((size_t)2048 * 256 * 4);
  unsigned short* BTb = (unsigned short*)alloc((size_t)8 * 128 * 256 * 2);
  float* dtcbuf = (float*)alloc((size_t)2048 * 64 * 4);
  float* dAcbuf = (float*)alloc((size_t)512 * 256 * 4);
  float* cdec   = (float*)alloc((size_t)512 * 4);
  float* CBbuf  = (float*)alloc((size_t)8 * 256 * 256 * 4);
  float* statesT = (float*)alloc((size_t)512 * 64 * 128 * 4);
  unsigned short* y2 = Wb_in;              // dead after in_proj GEMM
  unsigned short* prevb = hbuf;            // dead after in_proj GEMM (8 MB exact)

  (void)in_sizes; (void)n_in; (void)out_size; (void)ws_size;

  // weight conversion (every call; no caching allowed)
  f32_to_bf16_pad<<<(8576 * 2048 / 4 + 255) / 256, 256, 0, stream>>>(
      W_in, Wb_in, (long)8512 * 2048, (long)8576 * 2048);
  f32_to_bf16_pad<<<(2048 * 4096 / 4 + 255) / 256, 256, 0, stream>>>(
      W_out, Wb_out, (long)2048 * 4096, (long)2048 * 4096);

  // 1. input RMSNorm -> bf16
  rmsnorm_in<<<2048, 256, 0, stream>>>(x, rms_w, hbuf);

  // 2. in_proj: proj[2048,8512] = h @ W_in^T
  gemm_pipe<128, false><<<16 * 67, 256, 0, stream>>>(hbuf, Wb_in, proj, nullptr,
                                                     2048, 8512, 8512, 16, 67, 4);

  // 3. conv + SiLU + softplus(dt); emits BC fp32 + BTb bf16
  conv_silu_dt<<<dim3(18, 128), 256, 0, stream>>>(proj, conv_w, conv_b, dt_bias,
                                                  xsbuf, BCbuf, BTb, dtcbuf);

  // 4. per-(chunk,head) cumsum of dt*A; chunk decay
  scan_dA<<<512, 256, 0, stream>>>(dtcbuf, A_log, dAcbuf, cdec);

  // 5. CB = C @ B^T per chunk (row-major)
  cb_k<<<2048, 256, 0, stream>>>(BCbuf, CBbuf);

  // 6. MFMA chunk states
  ssd_states<<<512, 512, 0, stream>>>(xsbuf, BTb, dtcbuf, dAcbuf, statesT);

  // 7. inter-chunk recurrence -> prev states (bf16)
  ssd_scan<<<2048, 256, 0, stream>>>(statesT, prevb, cdec);

  // 8. MFMA Y_diag + Y_off + D*xs -> y (in-place over xs)
  ssd_diag_off<<<512, 512, 0, stream>>>(xsbuf, BCbuf, dtcbuf, dAcbuf, CBbuf,
                                        prevb, Dp, xsbuf);

  // 9. gated RMSNorm -> bf16
  gated_rmsnorm<<<2048, 256, 0, stream>>>(xsbuf, proj, norm_w, y2);

  // 10. out_proj + residual -> d_out
  gemm_pipe<64, true><<<32 * 16, 256, 0, stream>>>(y2, Wb_out, out, x,
                                                   4096, 2048, 2048, 32, 16, 4);
}

// Round 7
// 337.114 us; speedup vs baseline: 1.5822x; 1.0370x over previous
//
#include <hip/hip_runtime.h>
#include <stdint.h>

// ---------------------------------------------------------------------------
// FalconMamba2 SSM decoder layer, MI355X (gfx950) — round 7
// Round-6 + in_proj GEMM retiled to 192x128 (wave 96x64, MF=6) to balance
// LDS-read throughput vs MFMA (was 1.24:1 LDS-bound at wave 64x64).
// ---------------------------------------------------------------------------

typedef __bf16 bf16x8 __attribute__((ext_vector_type(8)));
typedef float  f32x4  __attribute__((ext_vector_type(4)));

#define DEVFN __device__ __forceinline__

DEVFN unsigned short f2b(float f) {
  uint32_t u = __builtin_bit_cast(uint32_t, f);
  u += 0x7fffu + ((u >> 16) & 1u);          // round-to-nearest-even
  return (unsigned short)(u >> 16);
}
DEVFN float b2f(unsigned short u) {
  uint32_t x = (uint32_t)u << 16;
  return __builtin_bit_cast(float, x);
}
DEVFN bf16x8 pack8(const float (&m)[8]) {
  bf16x8 r;
#pragma unroll
  for (int t = 0; t < 8; ++t) r[t] = (__bf16)m[t];
  return r;
}

// bijective XCD swizzle (m204) + GROUP-major supertiling
DEVFN void tile_map(int bid, int nwg, int nm, int nn, int grp, int& mt, int& nt) {
  const int q = nwg >> 3, r = nwg & 7;
  const int xcd = bid & 7, lid = bid >> 3;
  const int wg = (xcd < r ? xcd * (q + 1) : r * (q + 1) + (xcd - r) * q) + lid;
  const int per = grp * nn;
  const int g = wg / per;
  const int rem = wg - g * per;
  const int lim = nm - g * grp;
  const int gm = lim < grp ? lim : grp;
  mt = g * grp + rem % gm;
  nt = rem / gm;
}

// ---------------------------------------------------------------------------
__global__ void f32_to_bf16_pad(const float* __restrict__ src,
                                unsigned short* __restrict__ dst,
                                long srcElems, long dstElems) {
  const long i = ((long)blockIdx.x * 256 + threadIdx.x) * 4;
  if (i >= dstElems) return;
  ushort4 o;
  if (i < srcElems) {
    float4 v = *reinterpret_cast<const float4*>(src + i);
    o.x = f2b(v.x); o.y = f2b(v.y); o.z = f2b(v.z); o.w = f2b(v.w);
  } else {
    o.x = 0; o.y = 0; o.z = 0; o.w = 0;
  }
  *reinterpret_cast<ushort4*>(dst + i) = o;
}

// ---------------------------------------------------------------------------
// input RMSNorm: x[2048][2048] f32 -> h bf16 (rows >= 2048: zero pad for
// the 192-row GEMM tiles)
// ---------------------------------------------------------------------------
__global__ __launch_bounds__(256) void rmsnorm_in(
    const float* __restrict__ x, const float* __restrict__ w,
    unsigned short* __restrict__ h) {
  const int row = blockIdx.x;
  const int base = threadIdx.x * 8;
  if (row >= 2048) {
    ushort4 z = {0, 0, 0, 0};
    *reinterpret_cast<ushort4*>(h + (size_t)row * 2048 + base)     = z;
    *reinterpret_cast<ushort4*>(h + (size_t)row * 2048 + base + 4) = z;
    return;
  }
  const float* xr = x + (size_t)row * 2048;
  float4 v0 = *reinterpret_cast<const float4*>(xr + base);
  float4 v1 = *reinterpret_cast<const float4*>(xr + base + 4);
  float ss = v0.x*v0.x + v0.y*v0.y + v0.z*v0.z + v0.w*v0.w
           + v1.x*v1.x + v1.y*v1.y + v1.z*v1.z + v1.w*v1.w;
  __shared__ float red[4];
#pragma unroll
  for (int off = 32; off > 0; off >>= 1) ss += __shfl_xor(ss, off);
  if ((threadIdx.x & 63) == 0) red[threadIdx.x >> 6] = ss;
  __syncthreads();
  ss = red[0] + red[1] + red[2] + red[3];
  const float scale = rsqrtf(ss * (1.0f / 2048.0f) + 1e-5f);
  float vals[8] = {v0.x, v0.y, v0.z, v0.w, v1.x, v1.y, v1.z, v1.w};
  unsigned short o[8];
#pragma unroll
  for (int j = 0; j < 8; ++j) o[j] = f2b(vals[j] * scale * w[base + j]);
  ushort4 a, b;
  a.x = o[0]; a.y = o[1]; a.z = o[2]; a.w = o[3];
  b.x = o[4]; b.y = o[5]; b.z = o[6]; b.w = o[7];
  *reinterpret_cast<ushort4*>(h + (size_t)row * 2048 + base)     = a;
  *reinterpret_cast<ushort4*>(h + (size_t)row * 2048 + base + 4) = b;
}

// ---------------------------------------------------------------------------
// Pipelined bf16 GEMM, C[M,N] = A[M,K] @ B[N,K]^T (+res). Tile BM x 128,
// BK=64, 4 waves (2x2), wave tile (BM/2) x 64, MF = BM/32 A-frags per wave.
// Double-buffered LDS, counted vmcnt, raw s_barrier, XOR-swizzled chunks.
// A must have >= nm*BM rows (zero-padded); C rows guarded by Mc.
// ---------------------------------------------------------------------------
template<int BM, bool RES>
__global__ __launch_bounds__(256, 2) void gemm_pipe(
    const unsigned short* __restrict__ A, const unsigned short* __restrict__ B,
    float* __restrict__ C, const float* __restrict__ res,
    int K, int Mc, int Nc, int ldc, int nm, int nn, int grp) {
  constexpr int MF = BM / 32;
  __shared__ __align__(16) unsigned short As[2][BM * 64];
  __shared__ __align__(16) unsigned short Bs[2][128 * 64];
  int mt, nt;
  tile_map(blockIdx.x, nm * nn, nm, nn, grp, mt, nt);
  const int m0 = mt * BM;
  const int n0 = nt * 128;
  const int tid  = threadIdx.x;
  const int wid  = tid >> 6;
  const int lane = tid & 63;
  const int wm   = (wid >> 1) * (BM / 2);
  const int wn   = (wid & 1) * 64;
  const int lrow = lane & 15;
  const int lkc  = lane >> 4;             // k-chunk 0..3 (8 elems each)

  // stage: LDS slot (row r, chunk cc) holds global k-chunk cc^(r&7)
  auto stageA = [&](int buf, int k0) {
#pragma unroll
    for (int i = 0; i < MF; ++i) {
      const int ci = tid + i * 256;
      const int r = ci >> 3, cc = ci & 7;
      const int gc = cc ^ (r & 7);
      __builtin_amdgcn_global_load_lds(
          (const __attribute__((address_space(1))) void*)(A + (size_t)(m0 + r) * K + k0 + gc * 8),
          (__attribute__((address_space(3))) void*)(&As[buf][ci * 8]), 16, 0, 0);
    }
  };
  auto stageB = [&](int buf, int k0) {
#pragma unroll
    for (int i = 0; i < 4; ++i) {
      const int ci = tid + i * 256;
      const int r = ci >> 3, cc = ci & 7;
      const int gc = cc ^ (r & 7);
      __builtin_amdgcn_global_load_lds(
          (const __attribute__((address_space(1))) void*)(B + (size_t)(n0 + r) * K + k0 + gc * 8),
          (__attribute__((address_space(3))) void*)(&Bs[buf][ci * 8]), 16, 0, 0);
    }
  };

  f32x4 acc[MF][4] = {};
  const int nsteps = K >> 6;

  stageA(0, 0); stageB(0, 0);
  if (nsteps > 1) { stageA(1, 64); stageB(1, 64); }
  if (nsteps > 1) asm volatile("s_waitcnt vmcnt(%0)" :: "n"(MF + 4) : "memory");
  else            asm volatile("s_waitcnt vmcnt(0)" ::: "memory");
  __builtin_amdgcn_s_barrier();
  __builtin_amdgcn_sched_barrier(0);

  int cur = 0;
  for (int t = 0; t < nsteps; ++t) {
    bf16x8 af[MF][2], bf[4][2];
#pragma unroll
    for (int m = 0; m < MF; ++m)
#pragma unroll
      for (int kk = 0; kk < 2; ++kk) {
        const int row = wm + m * 16 + lrow;
        const int c = kk * 4 + lkc;
        af[m][kk] = *reinterpret_cast<const bf16x8*>(
            &As[cur][row * 64 + ((c ^ (row & 7)) * 8)]);
      }
#pragma unroll
    for (int n = 0; n < 4; ++n)
#pragma unroll
      for (int kk = 0; kk < 2; ++kk) {
        const int row = wn + n * 16 + lrow;
        const int c = kk * 4 + lkc;
        bf[n][kk] = *reinterpret_cast<const bf16x8*>(
            &Bs[cur][row * 64 + ((c ^ (row & 7)) * 8)]);
      }
    // all frag ds_reads must complete (into regs) before anyone overwrites cur
    asm volatile("s_waitcnt lgkmcnt(0)" ::: "memory");
    __builtin_amdgcn_sched_barrier(0);
    __builtin_amdgcn_s_barrier();
    if (t + 2 < nsteps) { stageA(cur, (t + 2) * 64); stageB(cur, (t + 2) * 64); }
    __builtin_amdgcn_s_setprio(1);
#pragma unroll
    for (int kk = 0; kk < 2; ++kk)
#pragma unroll
      for (int m = 0; m < MF; ++m)
#pragma unroll
        for (int n = 0; n < 4; ++n)
          acc[m][n] = __builtin_amdgcn_mfma_f32_16x16x32_bf16(af[m][kk], bf[n][kk], acc[m][n], 0, 0, 0);
    __builtin_amdgcn_s_setprio(0);
    if (t + 1 < nsteps) {
      // counted wait: t+1's MF+4 loads done; t+2's (if staged) stay in flight
      if (t + 2 < nsteps) asm volatile("s_waitcnt vmcnt(%0)" :: "n"(MF + 4) : "memory");
      else                asm volatile("s_waitcnt vmcnt(0)" ::: "memory");
      __builtin_amdgcn_sched_barrier(0);
      __builtin_amdgcn_s_barrier();
    }
    cur ^= 1;
  }

  // C/D layout: col = lane&15, row = (lane>>4)*4 + reg  [m89/m91 verified]
#pragma unroll
  for (int m = 0; m < MF; ++m) {
#pragma unroll
    for (int n = 0; n < 4; ++n) {
      const int col = n0 + wn + n * 16 + lrow;
      if (col < Nc) {
#pragma unroll
        for (int v = 0; v < 4; ++v) {
          const int row = m0 + wm + m * 16 + (lane >> 4) * 4 + v;
          if (row < Mc) {
            const size_t idx = (size_t)row * ldc + col;
            float val = acc[m][n][v];
            if (RES) val += res[idx];
            C[idx] = val;
          }
        }
      }
    }
  }
}

// ---------------------------------------------------------------------------
// causal depthwise conv(K=4) + SiLU; softplus(dt+bias). 16 l per thread.
// Emits BC fp32 and BTb bf16 ([c][n][s], B transposed) for MFMA states.
// ---------------------------------------------------------------------------
__global__ __launch_bounds__(256) void conv_silu_dt(
    const float* __restrict__ proj, const float* __restrict__ conv_w,
    const float* __restrict__ conv_b, const float* __restrict__ dt_bias,
    float* __restrict__ xs, float* __restrict__ BC,
    unsigned short* __restrict__ BTb, float* __restrict__ dtc) {
  const int cch = blockIdx.x * 256 + threadIdx.x;
  const int l0 = blockIdx.y * 16;
  if (cch < 4352) {
    const float4 w = *reinterpret_cast<const float4*>(conv_w + (size_t)cch * 4);
    const float b = conv_b[cch];
    const float* pcol = proj + 4096 + cch;
    float w0, w1, w2;
    w0 = (l0 >= 3) ? pcol[(size_t)(l0 - 3) * 8512] : 0.0f;
    w1 = (l0 >= 2) ? pcol[(size_t)(l0 - 2) * 8512] : 0.0f;
    w2 = (l0 >= 1) ? pcol[(size_t)(l0 - 1) * 8512] : 0.0f;
#pragma unroll
    for (int i = 0; i < 16; ++i) {
      const int l = l0 + i;
      const float cur = pcol[(size_t)l * 8512];
      float acc = b + w0 * w.x + w1 * w.y + w2 * w.z + cur * w.w;
      w0 = w1; w1 = w2; w2 = cur;
      acc = acc / (1.0f + __expf(-acc));   // silu
      if (cch < 4096) {
        xs[(size_t)l * 4096 + cch] = acc;
      } else {
        BC[(size_t)l * 256 + (cch - 4096)] = acc;
        if (cch < 4224) {                   // B channels -> transposed bf16
          const int n = cch - 4096;
          BTb[((size_t)((l >> 8) * 128) + n) * 256 + (l & 255)] = f2b(acc);
        }
      }
    }
  } else if (cch < 4416) {
    const int hh = cch - 4352;
    const float bias = dt_bias[hh];
#pragma unroll
    for (int i = 0; i < 16; ++i) {
      const int l = l0 + i;
      const float v = proj[(size_t)l * 8512 + 8448 + hh] + bias;
      dtc[(size_t)l * 64 + hh] = (v > 20.0f) ? v : log1pf(expf(v));
    }
  }
}

// ---------------------------------------------------------------------------
__global__ __launch_bounds__(256) void scan_dA(
    const float* __restrict__ dtc, const float* __restrict__ A_log,
    float* __restrict__ dAc, float* __restrict__ cdec) {
  const int bx = blockIdx.x;              // c*64 + h
  const int c = bx >> 6, h = bx & 63;
  const int l = threadIdx.x;
  __shared__ float buf[256];
  const float Ah = -expf(A_log[h]);
  buf[l] = dtc[(size_t)(c * 256 + l) * 64 + h] * Ah;
  __syncthreads();
  for (int off = 1; off < 256; off <<= 1) {
    const float t = (l >= off) ? buf[l - off] : 0.0f;
    __syncthreads();
    buf[l] += t;
    __syncthreads();
  }
  dAc[(size_t)bx * 256 + l] = buf[l];
  if (l == 255) cdec[bx] = expf(buf[255]);
}

// ---------------------------------------------------------------------------
// CB[c][l][s] = sum_n C[c,l,n] * B[c,s,n]   (row-major, G=1 head-shared)
// ---------------------------------------------------------------------------
__global__ __launch_bounds__(256) void cb_k(const float* __restrict__ BC,
                                            float* __restrict__ CB) {
  const int gl = blockIdx.x;              // c*256 + l
  const int c = gl >> 8;
  const int s = threadIdx.x;
  __shared__ float Crow[128];
  if (threadIdx.x < 128) Crow[threadIdx.x] = BC[(size_t)gl * 256 + 128 + threadIdx.x];
  __syncthreads();
  const float* Br = BC + (size_t)(c * 256 + s) * 256;
  float acc = 0.0f;
#pragma unroll 4
  for (int n = 0; n < 128; ++n) acc += Crow[n] * Br[n];
  CB[(size_t)gl * 256 + s] = acc;
}

// ---------------------------------------------------------------------------
// MFMA states: statesT[c][h][p][n] = sum_s (w*xs)[s,p] * B[s,n]
// ---------------------------------------------------------------------------
__global__ __launch_bounds__(512) void ssd_states(
    const float* __restrict__ xs, const unsigned short* __restrict__ BTb,
    const float* __restrict__ dtc, const float* __restrict__ dAc,
    float* __restrict__ statesT) {
  const int bx = blockIdx.x;              // c*64 + h
  const int c = bx >> 6, h = bx & 63;
  __shared__ __align__(16) unsigned short xwT[64 * 264];   // [p][s], +8 pad
  __shared__ float dAL[256], wLs[256];
  const int tid = threadIdx.x;
  const int lane = tid & 63;
  const int w = tid >> 6;

  if (tid < 256) dAL[tid] = dAc[(size_t)bx * 256 + tid];
  else           wLs[tid - 256] = dtc[(size_t)(c * 256 + (tid - 256)) * 64 + h];
  __syncthreads();
  if (tid < 256) wLs[tid] = __expf(dAL[255] - dAL[tid]) * wLs[tid];
  __syncthreads();
#pragma unroll
  for (int it = 0; it < 4; ++it) {
    const int gid = it * 512 + tid;
    const int p = gid & 63;
    const int s0 = (gid >> 6) * 8;
    bf16x8 r;
#pragma unroll
    for (int k = 0; k < 8; ++k)
      r[k] = (__bf16)(xs[(size_t)(c * 256 + s0 + k) * 4096 + h * 64 + p] * wLs[s0 + k]);
    *reinterpret_cast<bf16x8*>(&xwT[p * 264 + s0]) = r;
  }
  __syncthreads();

  const int pb = (w & 3) * 16;
  const int nb = (w >> 2) * 64;
  const int kcol = (lane >> 4) * 8;
  f32x4 acc[4] = {};
  for (int k = 0; k < 8; ++k) {
    bf16x8 av = *reinterpret_cast<const bf16x8*>(&xwT[(pb + (lane & 15)) * 264 + k * 32 + kcol]);
#pragma unroll
    for (int nf = 0; nf < 4; ++nf) {
      bf16x8 bv = *reinterpret_cast<const bf16x8*>(
          BTb + ((size_t)(c * 128) + nb + nf * 16 + (lane & 15)) * 256 + k * 32 + kcol);
      acc[nf] = __builtin_amdgcn_mfma_f32_16x16x32_bf16(av, bv, acc[nf], 0, 0, 0);
    }
  }
  const int rb = (lane >> 4) * 4;
#pragma unroll
  for (int nf = 0; nf < 4; ++nf) {
    const int n = nb + nf * 16 + (lane & 15);
#pragma unroll
    for (int v = 0; v < 4; ++v) {
      const int p = pb + rb + v;
      statesT[(size_t)bx * 8192 + p * 128 + n] = acc[nf][v];
    }
  }
}

// ---------------------------------------------------------------------------
// inter-chunk scan: emits prev-state (BEFORE chunk) as bf16 [c][h][p][n]
// ---------------------------------------------------------------------------
__global__ void ssd_scan(const float* __restrict__ statesT,
                         unsigned short* __restrict__ prevb,
                         const float* __restrict__ cdec) {
  const int i = blockIdx.x * 256 + threadIdx.x;   // < 64*8192
  const int h = i >> 13;
  const int r = i & 8191;
  float carry = 0.0f;
#pragma unroll
  for (int c = 0; c < 8; ++c) {
    const size_t idx = ((size_t)(c * 64 + h)) * 8192 + r;
    const float st = statesT[idx];
    prevb[idx] = f2b(carry);
    carry = carry * cdec[c * 64 + h] + st;
  }
}

// ---------------------------------------------------------------------------
// MFMA Y_diag + Y_off + D*xs -> y. block = (c,h), 512 thr, 8 waves.
// ---------------------------------------------------------------------------
__global__ __launch_bounds__(512) void ssd_diag_off(
    const float* xs, const float* __restrict__ BC,
    const float* __restrict__ dtc, const float* __restrict__ dAc,
    const float* __restrict__ CB, const unsigned short* __restrict__ prevb,
    const float* __restrict__ Dp, float* y) {
  const int bx = blockIdx.x;              // c*64 + h
  const int c = bx >> 6, h = bx & 63;
  __shared__ __align__(16) unsigned short xsT[64 * 264];   // [p][s], +8 pad
  __shared__ float dAL[256], dtL[256], vdt[256];
  const int tid = threadIdx.x;
  const int lane = tid & 63;
  const int w = tid >> 6;

  if (tid < 256) {
    dAL[tid] = dAc[(size_t)bx * 256 + tid];
    dtL[tid] = dtc[(size_t)(c * 256 + tid) * 64 + h];
  }
  __syncthreads();
  if (tid < 256) vdt[tid] = __expf(dAL[tid | 31] - dAL[tid]) * dtL[tid];
#pragma unroll
  for (int it = 0; it < 4; ++it) {
    const int gid = it * 512 + tid;
    const int p = gid & 63;
    const int s0 = (gid >> 6) * 8;
    bf16x8 r;
#pragma unroll
    for (int k = 0; k < 8; ++k)
      r[k] = (__bf16)xs[(size_t)(c * 256 + s0 + k) * 4096 + h * 64 + p];
    *reinterpret_cast<bf16x8*>(&xsT[p * 264 + s0]) = r;
  }
  __syncthreads();

  const int l1 = w * 32 + (lane & 15);
  const int l2 = l1 + 16;
  const int kcol = (lane >> 4) * 8;
  const float dA1 = dAL[l1], dA2 = dAL[l2];
  const float* CBr1 = CB + ((size_t)(c * 256) + l1) * 256;
  const float* CBr2 = CB + ((size_t)(c * 256) + l2) * 256;
  f32x4 acc[2][4] = {};

  // ---- Y_diag off-diagonal j-blocks
  for (int j = 0; j < w; ++j) {
    const int s0 = j * 32 + kcol;
    float cb1[8], cb2[8];
    *reinterpret_cast<float4*>(&cb1[0]) = *reinterpret_cast<const float4*>(CBr1 + s0);
    *reinterpret_cast<float4*>(&cb1[4]) = *reinterpret_cast<const float4*>(CBr1 + s0 + 4);
    *reinterpret_cast<float4*>(&cb2[0]) = *reinterpret_cast<const float4*>(CBr2 + s0);
    *reinterpret_cast<float4*>(&cb2[4]) = *reinterpret_cast<const float4*>(CBr2 + s0 + 4);
    const float a = dAL[j * 32 + 31];
    const float u1 = __expf(dA1 - a), u2 = __expf(dA2 - a);
    float m1[8], m2[8];
#pragma unroll
    for (int t = 0; t < 8; ++t) {
      const float uv = vdt[s0 + t];
      m1[t] = cb1[t] * (u1 * uv);
      m2[t] = cb2[t] * (u2 * uv);
    }
    bf16x8 a1 = pack8(m1), a2 = pack8(m2);
#pragma unroll
    for (int nf = 0; nf < 4; ++nf) {
      bf16x8 bv = *reinterpret_cast<const bf16x8*>(
          &xsT[(nf * 16 + (lane & 15)) * 264 + j * 32 + kcol]);
      acc[0][nf] = __builtin_amdgcn_mfma_f32_16x16x32_bf16(a1, bv, acc[0][nf], 0, 0, 0);
      acc[1][nf] = __builtin_amdgcn_mfma_f32_16x16x32_bf16(a2, bv, acc[1][nf], 0, 0, 0);
    }
  }
  // ---- diagonal block: direct exp + triangular select
  {
    const int s0 = w * 32 + kcol;
    float cb1[8], cb2[8];
    *reinterpret_cast<float4*>(&cb1[0]) = *reinterpret_cast<const float4*>(CBr1 + s0);
    *reinterpret_cast<float4*>(&cb1[4]) = *reinterpret_cast<const float4*>(CBr1 + s0 + 4);
    *reinterpret_cast<float4*>(&cb2[0]) = *reinterpret_cast<const float4*>(CBr2 + s0);
    *reinterpret_cast<float4*>(&cb2[4]) = *reinterpret_cast<const float4*>(CBr2 + s0 + 4);
    float m1[8], m2[8];
#pragma unroll
    for (int t = 0; t < 8; ++t) {
      const int s = s0 + t;
      const float e1 = __expf(fminf(dA1 - dAL[s], 0.0f)) * dtL[s];
      const float e2 = __expf(fminf(dA2 - dAL[s], 0.0f)) * dtL[s];
      m1[t] = (s <= l1) ? cb1[t] * e1 : 0.0f;
      m2[t] = (s <= l2) ? cb2[t] * e2 : 0.0f;
    }
    bf16x8 a1 = pack8(m1), a2 = pack8(m2);
#pragma unroll
    for (int nf = 0; nf < 4; ++nf) {
      bf16x8 bv = *reinterpret_cast<const bf16x8*>(
          &xsT[(nf * 16 + (lane & 15)) * 264 + w * 32 + kcol]);
      acc[0][nf] = __builtin_amdgcn_mfma_f32_16x16x32_bf16(a1, bv, acc[0][nf], 0, 0, 0);
      acc[1][nf] = __builtin_amdgcn_mfma_f32_16x16x32_bf16(a2, bv, acc[1][nf], 0, 0, 0);
    }
  }
  // ---- Y_off: A = C[l][n]*exp(dAl), B = prev[p][n] bf16 global
  {
    const float eA1 = __expf(dA1), eA2 = __expf(dA2);
    const float* Cr1 = BC + ((size_t)(c * 256) + l1) * 256 + 128;
    const float* Cr2 = BC + ((size_t)(c * 256) + l2) * 256 + 128;
    const unsigned short* pv = prevb + (size_t)bx * 8192;
#pragma unroll
    for (int q = 0; q < 4; ++q) {
      const int n0 = q * 32 + kcol;
      float c1[8], c2[8];
      *reinterpret_cast<float4*>(&c1[0]) = *reinterpret_cast<const float4*>(Cr1 + n0);
      *reinterpret_cast<float4*>(&c1[4]) = *reinterpret_cast<const float4*>(Cr1 + n0 + 4);
      *reinterpret_cast<float4*>(&c2[0]) = *reinterpret_cast<const float4*>(Cr2 + n0);
      *reinterpret_cast<float4*>(&c2[4]) = *reinterpret_cast<const float4*>(Cr2 + n0 + 4);
      float m1[8], m2[8];
#pragma unroll
      for (int t = 0; t < 8; ++t) { m1[t] = c1[t] * eA1; m2[t] = c2[t] * eA2; }
      bf16x8 a1 = pack8(m1), a2 = pack8(m2);
#pragma unroll
      for (int nf = 0; nf < 4; ++nf) {
        bf16x8 bv = *reinterpret_cast<const bf16x8*>(
            pv + (size_t)(nf * 16 + (lane & 15)) * 128 + n0);
        acc[0][nf] = __builtin_amdgcn_mfma_f32_16x16x32_bf16(a1, bv, acc[0][nf], 0, 0, 0);
        acc[1][nf] = __builtin_amdgcn_mfma_f32_16x16x32_bf16(a2, bv, acc[1][nf], 0, 0, 0);
      }
    }
  }
  // ---- epilogue: y = acc + D*xs
  const float Dh = Dp[h];
  const int rb = (lane >> 4) * 4;
#pragma unroll
  for (int mf = 0; mf < 2; ++mf) {
#pragma unroll
    for (int nf = 0; nf < 4; ++nf) {
      const int p = nf * 16 + (lane & 15);
#pragma unroll
      for (int v = 0; v < 4; ++v) {
        const int l = w * 32 + mf * 16 + rb + v;
        y[(size_t)(c * 256 + l) * 4096 + h * 64 + p] =
            acc[mf][nf][v] + Dh * b2f(xsT[p * 264 + l]);
      }
    }
  }
}

// ---------------------------------------------------------------------------
// gated RMSNorm: y2 = rmsnorm(y * silu(z)) * norm_w  -> bf16
// ---------------------------------------------------------------------------
__global__ __launch_bounds__(256) void gated_rmsnorm(
    const float* __restrict__ y, const float* __restrict__ proj,
    const float* __restrict__ nw, unsigned short* __restrict__ y2) {
  const int row = blockIdx.x;
  const float* yr = y + (size_t)row * 4096;
  const float* zr = proj + (size_t)row * 8512;    // z = cols 0..4095
  const int base = threadIdx.x * 16;
  float g[16];
  float ss = 0.0f;
#pragma unroll
  for (int j = 0; j < 16; j += 4) {
    const float4 yv = *reinterpret_cast<const float4*>(yr + base + j);
    const float4 zv = *reinterpret_cast<const float4*>(zr + base + j);
    const float a0 = yv.x * (zv.x / (1.0f + expf(-zv.x)));
    const float a1 = yv.y * (zv.y / (1.0f + expf(-zv.y)));
    const float a2 = yv.z * (zv.z / (1.0f + expf(-zv.z)));
    const float a3 = yv.w * (zv.w / (1.0f + expf(-zv.w)));
    g[j] = a0; g[j+1] = a1; g[j+2] = a2; g[j+3] = a3;
    ss += a0*a0 + a1*a1 + a2*a2 + a3*a3;
  }
  __shared__ float red[4];
#pragma unroll
  for (int off = 32; off > 0; off >>= 1) ss += __shfl_xor(ss, off);
  if ((threadIdx.x & 63) == 0) red[threadIdx.x >> 6] = ss;
  __syncthreads();
  ss = red[0] + red[1] + red[2] + red[3];
  const float scale = rsqrtf(ss * (1.0f / 4096.0f) + 1e-5f);
#pragma unroll
  for (int j = 0; j < 16; j += 4) {
    ushort4 o;
    o.x = f2b(g[j]   * scale * nw[base + j]);
    o.y = f2b(g[j+1] * scale * nw[base + j + 1]);
    o.z = f2b(g[j+2] * scale * nw[base + j + 2]);
    o.w = f2b(g[j+3] * scale * nw[base + j + 3]);
    *reinterpret_cast<ushort4*>(y2 + (size_t)row * 4096 + base + j) = o;
  }
}

// ---------------------------------------------------------------------------
extern "C" void kernel_launch(void* const* d_in, const int* in_sizes, int n_in,
                              void* d_out, int out_size, void* d_ws, size_t ws_size,
                              hipStream_t stream) {
  const float* x       = (const float*)d_in[0];
  const float* rms_w   = (const float*)d_in[1];
  const float* W_in    = (const float*)d_in[2];
  const float* conv_w  = (const float*)d_in[3];
  const float* conv_b  = (const float*)d_in[4];
  const float* dt_bias = (const float*)d_in[5];
  const float* A_log   = (const float*)d_in[6];
  const float* Dp      = (const float*)d_in[7];
  const float* norm_w  = (const float*)d_in[8];
  const float* W_out   = (const float*)d_in[9];
  float* out = (float*)d_out;

  char* ws = (char*)d_ws;
  size_t off = 0;
  auto alloc = [&](size_t bytes) {
    void* p = ws + off;
    off += (bytes + 255) & ~(size_t)255;
    return p;
  };
  unsigned short* Wb_in  = (unsigned short*)alloc((size_t)8576 * 2048 * 2);
  unsigned short* Wb_out = (unsigned short*)alloc((size_t)2048 * 4096 * 2);
  unsigned short* hbuf   = (unsigned short*)alloc((size_t)2112 * 2048 * 2); // M-pad for 192 tiles
  float* proj   = (float*)alloc((size_t)2048 * 8512 * 4);
  float* xsbuf  = (float*)alloc((size_t)2048 * 4096 * 4);   // xs, then y (in-place)
  float* BCbuf  = (float*)alloc((size_t)2048 * 256 * 4);
  unsigned short* BTb = (unsigned short*)alloc((size_t)8 * 128 * 256 * 2);
  float* dtcbuf = (float*)alloc((size_t)2048 * 64 * 4);
  float* dAcbuf = (float*)alloc((size_t)512 * 256 * 4);
  float* cdec   = (float*)alloc((size_t)512 * 4);
  float* CBbuf  = (float*)alloc((size_t)8 * 256 * 256 * 4);
  float* statesT = (float*)alloc((size_t)512 * 64 * 128 * 4);
  unsigned short* y2 = Wb_in;              // dead after in_proj GEMM
  unsigned short* prevb = hbuf;            // dead after in_proj GEMM

  (void)in_sizes; (void)n_in; (void)out_size; (void)ws_size;

  // weight conversion (every call; no caching allowed)
  f32_to_bf16_pad<<<(8576 * 2048 / 4 + 255) / 256, 256, 0, stream>>>(
      W_in, Wb_in, (long)8512 * 2048, (long)8576 * 2048);
  f32_to_bf16_pad<<<(2048 * 4096 / 4 + 255) / 256, 256, 0, stream>>>(
      W_out, Wb_out, (long)2048 * 4096, (long)2048 * 4096);

  // 1. input RMSNorm -> bf16 (rows 2048..2111 zero-padded)
  rmsnorm_in<<<2112, 256, 0, stream>>>(x, rms_w, hbuf);

  // 2. in_proj: proj[2048,8512] = h @ W_in^T  (192x128 tiles, 11x67 grid)
  gemm_pipe<192, false><<<11 * 67, 256, 0, stream>>>(hbuf, Wb_in, proj, nullptr,
                                                     2048, 2048, 8512, 8512,
                                                     11, 67, 4);

  // 3. conv + SiLU + softplus(dt); emits BC fp32 + BTb bf16
  conv_silu_dt<<<dim3(18, 128), 256, 0, stream>>>(proj, conv_w, conv_b, dt_bias,
                                                  xsbuf, BCbuf, BTb, dtcbuf);

  // 4. per-(chunk,head) cumsum of dt*A; chunk decay
  scan_dA<<<512, 256, 0, stream>>>(dtcbuf, A_log, dAcbuf, cdec);

  // 5. CB = C @ B^T per chunk (row-major)
  cb_k<<<2048, 256, 0, stream>>>(BCbuf, CBbuf);

  // 6. MFMA chunk states
  ssd_states<<<512, 512, 0, stream>>>(xsbuf, BTb, dtcbuf, dAcbuf, statesT);

  // 7. inter-chunk recurrence -> prev states (bf16)
  ssd_scan<<<2048, 256, 0, stream>>>(statesT, prevb, cdec);

  // 8. MFMA Y_diag + Y_off + D*xs -> y (in-place over xs)
  ssd_diag_off<<<512, 512, 0, stream>>>(xsbuf, BCbuf, dtcbuf, dAcbuf, CBbuf,
                                        prevb, Dp, xsbuf);

  // 9. gated RMSNorm -> bf16
  gated_rmsnorm<<<2048, 256, 0, stream>>>(xsbuf, proj, norm_w, y2);

  // 10. out_proj + residual -> d_out
  gemm_pipe<64, true><<<32 * 16, 256, 0, stream>>>(y2, Wb_out, out, x,
                                                   4096, 2048, 2048, 2048,
                                                   32, 16, 4);
}